// Round 8
// baseline (550.506 us; speedup 1.0000x reference)
//
#include <hip/hip_runtime.h>

typedef unsigned short ushort_t;
typedef short bf16x8 __attribute__((ext_vector_type(8)));
typedef float f32x4 __attribute__((ext_vector_type(4)));
typedef float f32x16 __attribute__((ext_vector_type(16)));

#define DEV __device__ __forceinline__

// round-half-up bf16 (2 ops)
DEV ushort_t f2bf(float f) {
  return (ushort_t)((__float_as_uint(f) + 0x8000u) >> 16);
}
// pack two floats -> 2 bf16 in one u32 (3 ops: add, add, v_perm_b32)
DEV unsigned pk_bf16(float lo, float hi) {
  unsigned a = __float_as_uint(lo) + 0x8000u;
  unsigned b = __float_as_uint(hi) + 0x8000u;
  return __builtin_amdgcn_perm(b, a, 0x07060302);  // {b.hi16, a.hi16}
}
// single-op packed cvt (RNE): lo16 = bf16(lo), hi16 = bf16(hi).
DEV unsigned cvtpk_bf16(float lo, float hi) {
  unsigned r;
  asm("v_cvt_pk_bf16_f32 %0, %1, %2" : "=v"(r) : "v"(lo), "v"(hi));
  return r;
}
DEV float bf2f(ushort_t h) {
  union { unsigned int u; float f; } v; v.u = ((unsigned int)h) << 16;
  return v.f;
}
DEV f32x4 mfma16(bf16x8 a, bf16x8 b, f32x4 c) {
  return __builtin_amdgcn_mfma_f32_16x16x32_bf16(a, b, c, 0, 0, 0);
}
DEV f32x16 mfma32(bf16x8 a, bf16x8 b, f32x16 c) {
  return __builtin_amdgcn_mfma_f32_32x32x16_bf16(a, b, c, 0, 0, 0);
}
// v_permlane32_swap_b32 (gfx950, verified R4):
// after pl32swap(a,b): a = [a_lo | b_lo], b = [a_hi | b_hi]  ([lo|hi] halves).
DEV void pl32swap(unsigned &a, unsigned &b) {
  asm("v_permlane32_swap_b32 %0, %1" : "+v"(a), "+v"(b));
}
typedef __attribute__((address_space(3))) void lds_void;
typedef const __attribute__((address_space(1))) void glb_void;
DEV void gl_lds16(const void* g, void* l) {
  __builtin_amdgcn_global_load_lds((glb_void*)g, (lds_void*)l, 16, 0, 0);
}

// ---------------------------------------------------------------------------
// bf16 GEMM v3: C = A[M,K] * BT[N,K]^T (+bias, +col-scale window).
// R7 post-mortem: dbuf at 128x128/256thr = 32 KB LDS -> 5 blocks/CU against
// a 6/CU grid -> ragged tail ate the dbuf gain (46 -> 50 us). Fix: co-design
// LDS with residency. 256x128 tile, 8 waves (512 thr, 4M x 2N wave grid),
// BK=32, double-buffered: LDS = 48 KB -> exactly 3 blocks/CU (144/160), and
// the big-GEMM grid 64x12 = 768 = exactly 3/CU. No tail. Same waves/CU (24),
// same per-wave work as before (4x4 frags, 16 MFMA + 8 ds_read_b128/iter),
// 3 gl_lds16/thread staging.
// Single-barrier dbuf schedule (flash-proven): stage(k+1) issued right after
// the barrier, flies across compute(k); barrier at iter k+1 drains it.
// SWAPPED-OPERAND MFMA (R6): acc = mfma16(bfr, af) puts output row on
// lane&15, 4 consecutive cols in regs -> uint2/float4 vector stores.
// T1 XCD remap (m-major in chunk): per-XCD set = 8 A-panels (2 MB) + B
// (<=1.5 MB) ~ L2-resident.
// ---------------------------------------------------------------------------
__global__ __launch_bounds__(512, 6)
void gemm_bt(const ushort_t* __restrict__ A, int lda,
             const ushort_t* __restrict__ BT,
             const float* __restrict__ bias,
             ushort_t* __restrict__ Cb, float* __restrict__ Cf,
             int ldc, int coff, int K, float scv, int sc_lo, int sc_hi)
{
  __shared__ __align__(16) ushort_t As[2][256 * 32];
  __shared__ __align__(16) ushort_t Bs[2][128 * 32];
  const int tid  = threadIdx.x;
  const int wave = tid >> 6, lane = tid & 63;
  const int quad = lane >> 4, r16 = lane & 15;
  // T1 remap (nwg % 8 == 0 at all call sites): logical n-fastest.
  const int nwg = gridDim.x * gridDim.y;
  const int lin = blockIdx.x + gridDim.x * blockIdx.y;
  const int logical = (lin & 7) * (nwg >> 3) + (lin >> 3);
  const int nbn = gridDim.y;
  const int mb = logical / nbn, nb = logical - mb * nbn;
  const int m0 = mb * 256, n0 = nb * 128;
  const int wm = (wave >> 1) * 64, wn = (wave & 1) * 64;

  f32x4 acc[4][4];
#pragma unroll
  for (int i = 0; i < 4; ++i)
#pragma unroll
    for (int j = 0; j < 4; ++j) acc[i][j] = (f32x4){0.f, 0.f, 0.f, 0.f};

  auto stage = [&](int kc, int buf) {
    // A tile 256x32 = 1024 chunks (16 B), 2 per thread.
#pragma unroll
    for (int l = 0; l < 2; ++l) {
      int c = l * 512 + tid;
      int row = c >> 2, e8 = (c & 3) * 8;
      gl_lds16(&A[(size_t)(m0 + row) * lda + kc + e8], &As[buf][c * 8]);
    }
    // B tile 128x32 = 512 chunks, 1 per thread.
    {
      int row = tid >> 2, e8 = (tid & 3) * 8;
      gl_lds16(&BT[(size_t)(n0 + row) * K + kc + e8], &Bs[buf][tid * 8]);
    }
  };

  stage(0, 0);
  const int NI = K >> 5;
  for (int ki = 0; ki < NI; ++ki) {
    const int cur = ki & 1;
    __syncthreads();                     // vmcnt(0): tile ki staged; fences
                                         // prev-iter LDS readers of buf^1
    if (ki + 1 < NI) stage((ki + 1) << 5, cur ^ 1);
    bf16x8 af[4], bfr[4];
#pragma unroll
    for (int i = 0; i < 4; ++i) {
      af[i]  = *(const bf16x8*)&As[cur][(wm + i * 16 + r16) * 32 + quad * 8];
      bfr[i] = *(const bf16x8*)&Bs[cur][(wn + i * 16 + r16) * 32 + quad * 8];
    }
#pragma unroll
    for (int mi = 0; mi < 4; ++mi)
#pragma unroll
      for (int ni = 0; ni < 4; ++ni)
        acc[mi][ni] = mfma16(bfr[ni], af[mi], acc[mi][ni]);   // SWAPPED
  }

  // epilogue (swapped layout): row = m0+wm+mi*16+r16 (one row/lane),
  // cols = n0+wn+ni*16+quad*4+{0..3} (regs) -> vector stores.
#pragma unroll
  for (int mi = 0; mi < 4; ++mi) {
    const int row = m0 + wm + mi * 16 + r16;
#pragma unroll
    for (int ni = 0; ni < 4; ++ni) {
      const int col = n0 + wn + ni * 16 + quad * 4;
      float4 bv = bias ? *(const float4*)&bias[col]
                       : make_float4(0.f, 0.f, 0.f, 0.f);
      float v[4];
#pragma unroll
      for (int r = 0; r < 4; ++r) {
        float s = (col + r >= sc_lo && col + r < sc_hi) ? scv : 1.0f;
        v[r] = (acc[mi][ni][r] + (&bv.x)[r]) * s;
      }
      if (Cf) {
        *(float4*)&Cf[(size_t)row * ldc + coff + col] =
            make_float4(v[0], v[1], v[2], v[3]);
      } else {
        uint2 pk;
        pk.x = cvtpk_bf16(v[0], v[1]);
        pk.y = cvtpk_bf16(v[2], v[3]);
        *(uint2*)&Cb[(size_t)row * ldc + coff + col] = pk;
      }
    }
  }
}

// ---------------------------------------------------------------------------
// gemm_proj: steps 5+6 merged (R5); dbuf + swapped epilogue (R6/R7 version,
// kept: 512 blocks = 2/CU, under its 5-block LDS cap -> no tail here).
// ---------------------------------------------------------------------------
__global__ __launch_bounds__(256)
void gemm_proj(const ushort_t* __restrict__ rB,
               const ushort_t* __restrict__ hT, const ushort_t* __restrict__ lT,
               const float* __restrict__ hb, const float* __restrict__ lb,
               ushort_t* __restrict__ y)
{
  __shared__ __align__(16) ushort_t As[2][128 * 32];
  __shared__ __align__(16) ushort_t Bs[2][128 * 32];
  const int tid  = threadIdx.x;
  const int wave = tid >> 6, lane = tid & 63;
  const int quad = lane >> 4, r16 = lane & 15;
  // T1 remap, n-fastest (nwg = 512)
  const int lin = blockIdx.x + 128 * blockIdx.y;
  const int logical = (lin & 7) * 64 + (lin >> 3);
  const int nidx = logical & 3, m0 = (logical >> 2) * 128;
  const int sel = nidx >> 1, n0 = (nidx & 1) * 128;
  const ushort_t* A  = rB + sel * 256;
  const ushort_t* BT = sel ? lT : hT;
  const float* bias  = sel ? lb : hb;
  const int coff = sel * 256;
  const int wm = (wave >> 1) * 64, wn = (wave & 1) * 64;

  f32x4 acc[4][4];
#pragma unroll
  for (int i = 0; i < 4; ++i)
#pragma unroll
    for (int j = 0; j < 4; ++j) acc[i][j] = (f32x4){0.f, 0.f, 0.f, 0.f};

  auto stage = [&](int kc, int buf) {
#pragma unroll
    for (int p = 0; p < 4; ++p) {
      int wp = p * 4 + wave;
      int lc = ((wp & 7) << 6) + lane;
      int row = lc >> 2, e8 = (lc & 3) * 8;
      if (wp < 8) gl_lds16(&A[(size_t)(m0 + row) * 512 + kc + e8], &As[buf][lc * 8]);
      else        gl_lds16(&BT[(size_t)(n0 + row) * 256 + kc + e8], &Bs[buf][lc * 8]);
    }
  };

  stage(0, 0);
  for (int ki = 0; ki < 8; ++ki) {
    const int cur = ki & 1;
    __syncthreads();
    if (ki + 1 < 8) stage((ki + 1) << 5, cur ^ 1);
    bf16x8 af[4], bfr[4];
#pragma unroll
    for (int i = 0; i < 4; ++i) {
      af[i]  = *(const bf16x8*)&As[cur][(wm + i * 16 + r16) * 32 + quad * 8];
      bfr[i] = *(const bf16x8*)&Bs[cur][(wn + i * 16 + r16) * 32 + quad * 8];
    }
#pragma unroll
    for (int mi = 0; mi < 4; ++mi)
#pragma unroll
      for (int ni = 0; ni < 4; ++ni)
        acc[mi][ni] = mfma16(bfr[ni], af[mi], acc[mi][ni]);   // SWAPPED
  }

#pragma unroll
  for (int mi = 0; mi < 4; ++mi) {
    const int row = m0 + wm + mi * 16 + r16;
#pragma unroll
    for (int ni = 0; ni < 4; ++ni) {
      const int col = n0 + wn + ni * 16 + quad * 4;
      float4 bv = *(const float4*)&bias[col];
      uint2 pk;
      pk.x = cvtpk_bf16(acc[mi][ni][0] + bv.x, acc[mi][ni][1] + bv.y);
      pk.y = cvtpk_bf16(acc[mi][ni][2] + bv.z, acc[mi][ni][3] + bv.w);
      *(uint2*)&y[(size_t)row * 512 + coff + col] = pk;
    }
  }
}

// ---------------------------------------------------------------------------
// Flash attention v10b: QG independent 32-query groups per wave (templated).
// (unchanged from R5 -- see that round's notes.)
// ---------------------------------------------------------------------------
template<int QG>
__global__ __launch_bounds__(256, 2)
void flash_attn9(const ushort_t* __restrict__ Q, int qs, int q_ch,
                 const ushort_t* __restrict__ Kg, int ks, int k_ch,
                 const ushort_t* __restrict__ vT,
                 ushort_t* __restrict__ O, int os, int o_ch,
                 int N)
{
  // [buf][64 rows][64 bf16] ; K rows = keys (cols d), V rows = d (cols keys)
  __shared__ __align__(16) ushort_t Ks[2][64 * 64];
  __shared__ __align__(16) ushort_t Vs[2][64 * 64];

  const int H = gridDim.y;
  const int tid = threadIdx.x, wave = tid >> 6, lane = tid & 63;
  const int c = lane & 31, hh = lane >> 5;

  // T1: chunked XCD remap (bijective; nwg % 8 == 0).
  const int nwg = gridDim.x * H * gridDim.z;
  const int lin = blockIdx.x + gridDim.x * (blockIdx.y + H * blockIdx.z);
  const int logical = (lin & 7) * (nwg >> 3) + (lin >> 3);
  const int QBS = 8 / QG;                  // q-blocks per (b,h)
  const int qb = logical & (QBS - 1);
  const int t8 = logical / QBS;
  const int b = (H == 8) ? (t8 >> 3) : (t8 >> 2);
  const int h = t8 - b * H;
  const int q0 = qb * (128 * QG) + wave * (32 * QG);

  // Q fragments: B-operand layout B[k=d][n=query]: lane (hh,c) holds
  // query q0+qg*32+c, d = s*16 + hh*8 + j -> qf[qg][s] at byte-col s*16+hh*8.
  bf16x8 qf[QG][4];
#pragma unroll
  for (int qg = 0; qg < QG; ++qg) {
    const ushort_t* qp =
        Q + ((size_t)b * N + q0 + qg * 32 + c) * qs + q_ch + h * 64 + hh * 8;
#pragma unroll
    for (int s = 0; s < 4; ++s) qf[qg][s] = *(const bf16x8*)&qp[s * 16];
  }
  const ushort_t* kbase = Kg + ((size_t)b * N) * ks + k_ch + h * 64;
  const ushort_t* vbase = vT + ((size_t)(b * H + h) * 64) * N;

  f32x16 oacc[QG][2];
#pragma unroll
  for (int qg = 0; qg < QG; ++qg)
#pragma unroll
    for (int i = 0; i < 16; ++i) { oacc[qg][0][i] = 0.f; oacc[qg][1][i] = 0.f; }
  float l_acc[QG];
#pragma unroll
  for (int qg = 0; qg < QG; ++qg) l_acc[qg] = 0.f;

  auto stage = [&](int s0, int buf) {
#pragma unroll
    for (int p = 0; p < 4; ++p) {
      int wp = p * 4 + wave;                 // 0..15: 0..7 -> K, 8..15 -> V
      int lc = ((wp & 7) << 6) + lane;       // chunk 0..511 within tile
      int row = lc >> 3, cc = lc & 7;
      int e8 = ((cc ^ (row & 7)) * 8);       // inverse-swizzled SOURCE chunk
      if (wp < 8) gl_lds16(kbase + (size_t)(s0 + row) * ks + e8, &Ks[buf][lc * 8]);
      else        gl_lds16(vbase + (size_t)row * N + s0 + e8,    &Vs[buf][lc * 8]);
    }
  };

  stage(0, 0);
  const int NT = N >> 6;
  for (int it = 0; it < NT; ++it) {
    const int cur = it & 1;
    __syncthreads();                     // vmcnt(0) drain: tile `it` staged;
                                         // also fences prev-iter LDS readers
    if (it + 1 < NT) stage((it + 1) << 6, cur ^ 1);

    bf16x8 Bf[QG][4];                    // PV B-operand, k-steps of 16 keys
#pragma unroll
    for (int kb = 0; kb < 2; ++kb) {
      // K fragments shared across the QG query groups.
      const int krow = kb * 32 + c;
      const ushort_t* kr = &Ks[cur][krow * 64];
      bf16x8 kf[4];
#pragma unroll
      for (int s = 0; s < 4; ++s)
        kf[s] = *(const bf16x8*)&kr[(((s << 1) + hh) ^ (krow & 7)) * 8];

#pragma unroll
      for (int qg = 0; qg < QG; ++qg) {
        // S^T block: A = K rows (m = key kb*32 + (lane&31)), B = Q[qg].
        f32x16 z;
#pragma unroll
        for (int i = 0; i < 16; ++i) z[i] = 0.f;
#pragma unroll
        for (int s = 0; s < 4; ++s) z = mfma32(kf[s], qf[qg][s], z);
        // exp + pack: reg r <-> key kb*32 + (r&3) + 8*(r>>2) + 4*hh
        float ts = 0.f;
        unsigned W[8];
#pragma unroll
        for (int t = 0; t < 8; ++t) {
          float p0 = __builtin_amdgcn_exp2f(z[2 * t]);
          float p1 = __builtin_amdgcn_exp2f(z[2 * t + 1]);
          ts += p0 + p1;
          W[t] = cvtpk_bf16(p0, p1);
        }
        l_acc[qg] += ts;
        // B[k=hh*8+j][n=c] per k-step, element i = keys {s*16+hh*8+2i, +1}:
        //  u0=[W0_lo|W2_lo] u1=[W1_lo|W3_lo] u2=[W0_hi|W2_hi] u3=[W1_hi|W3_hi]
        // swap(a,b): a=[a_lo|b_lo], b=[a_hi|b_hi] -> swap(W0,W2)=(u0,u2),
        // swap(W1,W3)=(u1,u3); W4..W7 for the second k-step.  [verified R4]
        union U8 { bf16x8 f; unsigned u[4]; } f0, f1;
        unsigned a0 = W[0], b0 = W[2]; pl32swap(a0, b0);
        unsigned a1 = W[1], b1 = W[3]; pl32swap(a1, b1);
        f0.u[0] = a0; f0.u[1] = a1; f0.u[2] = b0; f0.u[3] = b1;
        unsigned a2 = W[4], b2 = W[6]; pl32swap(a2, b2);
        unsigned a3 = W[5], b3 = W[7]; pl32swap(a3, b3);
        f1.u[0] = a2; f1.u[1] = a3; f1.u[2] = b2; f1.u[3] = b3;
        Bf[qg][kb * 2]     = f0.f;
        Bf[qg][kb * 2 + 1] = f1.f;
      }
    }

    // PV: O^T = mfma32(A = V^T (m = d), B = P), k-steps of 16 keys; V
    // fragments shared across query groups.
#pragma unroll
    for (int db = 0; db < 2; ++db) {
      const int vrow = db * 32 + c;
      const ushort_t* vr = &Vs[cur][vrow * 64];
      bf16x8 vf[4];
#pragma unroll
      for (int s = 0; s < 4; ++s)
        vf[s] = *(const bf16x8*)&vr[(((s << 1) + hh) ^ (vrow & 7)) * 8];
#pragma unroll
      for (int qg = 0; qg < QG; ++qg)
#pragma unroll
        for (int s = 0; s < 4; ++s)
          oacc[qg][db] = mfma32(vf[s], Bf[qg][s], oacc[qg][db]);
    }
  }

  // epilogue: l(query c) = l_acc(h0) + l_acc(h1); O^T reg r of dblk db is
  // d = db*32 + (r&3) + 8*(r>>2) + 4*hh, query = c.
#pragma unroll
  for (int qg = 0; qg < QG; ++qg) {
    float l = l_acc[qg] + __shfl_xor(l_acc[qg], 32);
    float inv = 1.f / l;
    ushort_t* op = O + ((size_t)b * N + q0 + qg * 32 + c) * os + o_ch + h * 64;
#pragma unroll
    for (int db = 0; db < 2; ++db) {
#pragma unroll
      for (int g = 0; g < 4; ++g) {
        uint2 pkv;
        pkv.x = cvtpk_bf16(oacc[qg][db][4 * g + 0] * inv, oacc[qg][db][4 * g + 1] * inv);
        pkv.y = cvtpk_bf16(oacc[qg][db][4 * g + 2] * inv, oacc[qg][db][4 * g + 3] * inv);
        *(uint2*)&op[db * 32 + g * 8 + hh * 4] = pkv;
      }
    }
  }
}

// ---------------------------------------------------------------------------
// V transpose: in [B*N][ld] bf16 (channel ch, head h) -> out [B*H][64][N]
// ---------------------------------------------------------------------------
__global__ __launch_bounds__(256)
void transpose_v(const ushort_t* __restrict__ in, int ld, int ch,
                 ushort_t* __restrict__ out, int N, int H)
{
  __shared__ __align__(16) ushort_t T[64][72];
  const int s0 = blockIdx.x * 64, h = blockIdx.y, b = blockIdx.z;
  const int tid = threadIdx.x;
#pragma unroll
  for (int p = 0; p < 2; ++p) {
    int c = p * 256 + tid;
    int sr = c >> 3, d0 = (c & 7) * 8;
    *(uint4*)&T[sr][d0] =
        *(const uint4*)&in[((size_t)b * N + s0 + sr) * ld + ch + h * 64 + d0];
  }
  __syncthreads();
  const int d = tid >> 2, sp = (tid & 3) * 16;
  union { uint4 v; ushort_t u[8]; } A, B;
#pragma unroll
  for (int j = 0; j < 8; ++j) { A.u[j] = T[sp + j][d]; B.u[j] = T[sp + 8 + j][d]; }
  ushort_t* op = out + ((size_t)(b * H + h) * 64 + d) * N + s0 + sp;
  *(uint4*)&op[0] = A.v;
  *(uint4*)&op[8] = B.v;
}

// ---------------------------------------------------------------------------
// hifi window attention (2x2 windows, 4 heads). qkv rows stride ld; per-token
// layout [3][4 heads][64]. Output stride 512, cols 0..255.
// (q here is NOT pre-scaled by the GEMM; keeps its own 0.125 + __expf.)
// ---------------------------------------------------------------------------
__global__ __launch_bounds__(256)
void hifi_win(const ushort_t* __restrict__ qkv, int ld, ushort_t* __restrict__ out)
{
  const int bg = blockIdx.x;
  const int b = bg >> 8, g = bg & 255;
  const int head = threadIdx.x >> 6, lane = threadIdx.x & 63;
  const int gh = g >> 4, gw = g & 15;

  int n[4];
  float q[4], k[4], v[4];
#pragma unroll
  for (int t = 0; t < 4; ++t) {
    n[t] = (gh * 2 + (t >> 1)) * 32 + gw * 2 + (t & 1);
    size_t base = ((size_t)b * 1024 + n[t]) * ld + head * 64 + lane;
    q[t] = bf2f(qkv[base]);
    k[t] = bf2f(qkv[base + 256]);
    v[t] = bf2f(qkv[base + 512]);
  }
  float sc[4][4];
#pragma unroll
  for (int t = 0; t < 4; ++t)
#pragma unroll
    for (int s = 0; s < 4; ++s) {
      float p = q[t] * k[s];
#pragma unroll
      for (int off = 32; off >= 1; off >>= 1) p += __shfl_xor(p, off);
      sc[t][s] = p * 0.125f;
    }
#pragma unroll
  for (int t = 0; t < 4; ++t) {
    float m = fmaxf(fmaxf(sc[t][0], sc[t][1]), fmaxf(sc[t][2], sc[t][3]));
    float p0 = __expf(sc[t][0] - m), p1 = __expf(sc[t][1] - m);
    float p2 = __expf(sc[t][2] - m), p3 = __expf(sc[t][3] - m);
    float sum = p0 + p1 + p2 + p3;
    float o = (p0 * v[0] + p1 * v[1] + p2 * v[2] + p3 * v[3]) / sum;
    out[((size_t)b * 1024 + n[t]) * 512 + head * 64 + lane] = f2bf(o);
  }
}

// ---------------------------------------------------------------------------
// Merged weight prep: 7 transposes W[K][N] fp32 -> WT[N][K] bf16 in one launch.
// ---------------------------------------------------------------------------
struct WEnt { const float* W; ushort_t* WT; int K; int N; };
struct WArgs { WEnt e[7]; };

__global__ __launch_bounds__(256)
void w_prep(WArgs a)
{
  WEnt w = a.e[blockIdx.z];
  if ((int)blockIdx.x >= (w.K >> 6) || (int)blockIdx.y >= (w.N >> 6)) return;
  __shared__ float T[64][65];
  const int k0 = blockIdx.x * 64, n0 = blockIdx.y * 64;
  const int tid = threadIdx.x;
#pragma unroll
  for (int p = 0; p < 4; ++p) {
    int c = p * 256 + tid;
    int kr = c >> 4, f4 = (c & 15) * 4;
    float4 v = *(const float4*)&w.W[(size_t)(k0 + kr) * w.N + n0 + f4];
    T[f4 + 0][kr] = v.x; T[f4 + 1][kr] = v.y;
    T[f4 + 2][kr] = v.z; T[f4 + 3][kr] = v.w;
  }
  __syncthreads();
  const int nl = tid >> 2, kp = (tid & 3) * 16;
  union { uint4 v; ushort_t u[8]; } A, B;
#pragma unroll
  for (int j = 0; j < 8; ++j) {
    A.u[j] = f2bf(T[nl][kp + j]);
    B.u[j] = f2bf(T[nl][kp + 8 + j]);
  }
  ushort_t* op = w.WT + (size_t)(n0 + nl) * w.K + k0 + kp;
  *(uint4*)&op[0] = A.v;
  *(uint4*)&op[8] = B.v;
}

// xpe = bf16(x + pos_emb), vectorized x4
__global__ void add_pos(const float* __restrict__ x, const float* __restrict__ pos,
                        ushort_t* __restrict__ xpe)
{
  int idx = blockIdx.x * 256 + threadIdx.x;
  int e = idx * 4;
  float4 xv = *(const float4*)&x[e];
  float4 pv = *(const float4*)&pos[e & (512 * 1024 - 1)];
  uint2 pk;
  pk.x = pk_bf16(xv.x + pv.x, xv.y + pv.y);
  pk.y = pk_bf16(xv.z + pv.z, xv.w + pv.w);
  *(uint2*)&xpe[e] = pk;
}

extern "C" void kernel_launch(void* const* d_in, const int* in_sizes, int n_in,
                              void* d_out, int out_size, void* d_ws, size_t ws_size,
                              hipStream_t stream)
{
  const float* x         = (const float*)d_in[0];
  const float* pos       = (const float*)d_in[1];
  const float* l_q_w     = (const float*)d_in[2];
  const float* l_kv_w    = (const float*)d_in[3];
  const float* l_proj_w  = (const float*)d_in[4];
  const float* l_proj_b  = (const float*)d_in[5];
  const float* h_qkv_w   = (const float*)d_in[6];
  const float* h_proj_w  = (const float*)d_in[7];
  const float* h_proj_b  = (const float*)d_in[8];
  const float* in_proj_w = (const float*)d_in[9];
  const float* in_proj_b = (const float*)d_in[10];
  const float* out_proj_w= (const float*)d_in[11];
  const float* out_proj_b= (const float*)d_in[12];
  float* out = (float*)d_out;

  // 0.125 * log2(e): flash_attn uses exp2 directly.
  const float QSCALE = 0.125f * 1.44269504f;

  char* ws = (char*)d_ws;
  ushort_t* xpe = (ushort_t*)(ws);                       // 16 MB @ 0
  ushort_t* y   = (ushort_t*)(ws + (size_t)16777216);    // 16 MB @ 16M
  ushort_t* F   = (ushort_t*)(ws + (size_t)33554432);    // 48 MB @ 32M (fused acts)
  ushort_t* rB  = (ushort_t*)(ws + (size_t)83886080);    // 16 MB @ 80M
  ushort_t* wb  = (ushort_t*)(ws + (size_t)100663296);   // ~4 MB @ 96M (weights)

  // fused BT for the xpe GEMM: rows [0,768)=h_qkv, [768,1024)=l_q, [1024,1536)=l_kv
  ushort_t* F_T      = wb;                        // 1536 x 512
  ushort_t* h_projT  = wb + 786432;               // 256 x 256
  ushort_t* l_projT  = wb + 851968;               // 256 x 256
  ushort_t* in_projT = wb + 917504;               // 1536 x 512
  ushort_t* out_projT= wb + 1703936;              // 512 x 512

  const int M = 16384;
  ushort_t* vT_lo = xpe;   // 8 MB; xpe dead after fused GEMM
  ushort_t* vT_m  = rB;    // 16 MB; rB dead after lproj

  WArgs wa;
  wa.e[0] = {h_qkv_w,   F_T,                 512, 768};
  wa.e[1] = {l_q_w,     F_T + 768 * 512,     512, 256};
  wa.e[2] = {l_kv_w,    F_T + 1024 * 512,    512, 512};
  wa.e[3] = {h_proj_w,  h_projT,             256, 256};
  wa.e[4] = {l_proj_w,  l_projT,             256, 256};
  wa.e[5] = {in_proj_w, in_projT,            512, 1536};
  wa.e[6] = {out_proj_w,out_projT,           512, 512};
  w_prep<<<dim3(8, 24, 7), dim3(256), 0, stream>>>(wa);

  add_pos<<<dim3(8192), dim3(256), 0, stream>>>(x, pos, xpe);

  // 1. fused qkv GEMM: [M,512] x [512,1536] -> F (lofi q cols pre-scaled)
  //    256x128 tiles: grid 64x12 = 768 blocks = exactly 3/CU (no tail)
  gemm_bt<<<dim3(M / 256, 12), dim3(512), 0, stream>>>(
      xpe, 512, F_T, nullptr, F, nullptr, 1536, 0, 512, QSCALE, 768, 1024);
  // 2. hifi window attention -> rB cols [0,256)
  hifi_win<<<dim3(4096), dim3(256), 0, stream>>>(F, 1536, rB);
  // 3. transpose lofi V (F cols 1280..1535) -> vT_lo (xpe region, now dead)
  transpose_v<<<dim3(16, 4, 16), dim3(256), 0, stream>>>(
      F, 1536, 1280, vT_lo, 1024, 4);
  // 4. lofi attention (4 heads) -> rB cols [256,512)   (QG=1: 512 blocks)
  flash_attn9<1><<<dim3(8, 4, 16), dim3(256), 0, stream>>>(
      F, 1536, 768, F, 1536, 1024, vT_lo, rB, 512, 256, 1024);
  // 5+6. hifi & lofi proj merged -> y  (512 blocks = 2/CU)
  gemm_proj<<<dim3(128, 4), dim3(256), 0, stream>>>(
      rB, h_projT, l_projT, h_proj_b, l_proj_b, y);
  // 7. mha qkv: [M,512] x [512,1536] -> F (q cols pre-scaled)
  gemm_bt<<<dim3(M / 256, 12), dim3(512), 0, stream>>>(
      y, 512, in_projT, in_proj_b, F, nullptr, 1536, 0, 512, QSCALE, 0, 512);
  // 8. transpose mha V (F cols 1024..1535) -> vT_m (rB dead now)
  transpose_v<<<dim3(16, 8, 16), dim3(256), 0, stream>>>(
      F, 1536, 1024, vT_m, 1024, 8);
  // 9. mha attention (8 heads) -> xpe region [M,512]  (QG=2: 64 q/wave,
  //    512 blocks = 2/CU; two independent chains per wave)
  flash_attn9<2><<<dim3(4, 8, 16), dim3(256), 0, stream>>>(
      F, 1536, 0, F, 1536, 512, vT_m, xpe, 512, 0, 1024);
  // 10. out proj -> d_out fp32 (grid 64x4 = 256 blocks = 1/CU exact)
  gemm_bt<<<dim3(M / 256, 4), dim3(512), 0, stream>>>(
      xpe, 512, out_projT, out_proj_b, nullptr, out, 512, 0, 512, 1.0f, 0, 0);
}

// Round 9
// 333.956 us; speedup vs baseline: 1.6484x; 1.6484x over previous
//
#include <hip/hip_runtime.h>

typedef unsigned short ushort_t;
typedef short bf16x8 __attribute__((ext_vector_type(8)));
typedef float f32x4 __attribute__((ext_vector_type(4)));
typedef float f32x16 __attribute__((ext_vector_type(16)));

#define DEV __device__ __forceinline__

// round-half-up bf16 (2 ops)
DEV ushort_t f2bf(float f) {
  return (ushort_t)((__float_as_uint(f) + 0x8000u) >> 16);
}
// pack two floats -> 2 bf16 in one u32 (3 ops: add, add, v_perm_b32)
DEV unsigned pk_bf16(float lo, float hi) {
  unsigned a = __float_as_uint(lo) + 0x8000u;
  unsigned b = __float_as_uint(hi) + 0x8000u;
  return __builtin_amdgcn_perm(b, a, 0x07060302);  // {b.hi16, a.hi16}
}
// single-op packed cvt (RNE): lo16 = bf16(lo), hi16 = bf16(hi).
DEV unsigned cvtpk_bf16(float lo, float hi) {
  unsigned r;
  asm("v_cvt_pk_bf16_f32 %0, %1, %2" : "=v"(r) : "v"(lo), "v"(hi));
  return r;
}
DEV float bf2f(ushort_t h) {
  union { unsigned int u; float f; } v; v.u = ((unsigned int)h) << 16;
  return v.f;
}
DEV f32x4 mfma16(bf16x8 a, bf16x8 b, f32x4 c) {
  return __builtin_amdgcn_mfma_f32_16x16x32_bf16(a, b, c, 0, 0, 0);
}
DEV f32x16 mfma32(bf16x8 a, bf16x8 b, f32x16 c) {
  return __builtin_amdgcn_mfma_f32_32x32x16_bf16(a, b, c, 0, 0, 0);
}
// v_permlane32_swap_b32 (gfx950, verified R4):
// after pl32swap(a,b): a = [a_lo | b_lo], b = [a_hi | b_hi]  ([lo|hi] halves).
DEV void pl32swap(unsigned &a, unsigned &b) {
  asm("v_permlane32_swap_b32 %0, %1" : "+v"(a), "+v"(b));
}
typedef __attribute__((address_space(3))) void lds_void;
typedef const __attribute__((address_space(1))) void glb_void;
DEV void gl_lds16(const void* g, void* l) {
  __builtin_amdgcn_global_load_lds((glb_void*)g, (lds_void*)l, 16, 0, 0);
}

// ---------------------------------------------------------------------------
// bf16 GEMM v3b: C = A[M,K] * BT[N,K]^T (+bias, +col-scale window).
// 256x128 tile, 8 waves (512 thr), BK=32, double-buffered: 48 KB LDS ->
// 3 blocks/CU; big-GEMM grid 768 = exactly 3/CU, no tail.
// R8 post-mortem: __launch_bounds__(512, 6) forced the allocator into an
// unreachable occupancy bucket -> VGPR clamped to 40 -> the 64-reg acc
// spilled to scratch (WRITE_SIZE 49 -> 447 MB, 146 us). FIX: plain
// __launch_bounds__(512); R7's identical per-wave footprint measured 76
// VGPR unforced, which supports 6 waves/SIMD on its own. NEVER demand
// occupancy the register footprint can't provably meet.
// Single-barrier dbuf (flash-proven): stage(k+1) issued right after the
// barrier, flies across compute(k). SWAPPED-OPERAND MFMA epilogue (R6):
// row on lane&15, 4 consecutive cols in regs -> uint2/float4 stores.
// T1 XCD remap (m-major in chunk): per-XCD set ~ L2-resident.
// ---------------------------------------------------------------------------
__global__ __launch_bounds__(512)
void gemm_bt(const ushort_t* __restrict__ A, int lda,
             const ushort_t* __restrict__ BT,
             const float* __restrict__ bias,
             ushort_t* __restrict__ Cb, float* __restrict__ Cf,
             int ldc, int coff, int K, float scv, int sc_lo, int sc_hi)
{
  __shared__ __align__(16) ushort_t As[2][256 * 32];
  __shared__ __align__(16) ushort_t Bs[2][128 * 32];
  const int tid  = threadIdx.x;
  const int wave = tid >> 6, lane = tid & 63;
  const int quad = lane >> 4, r16 = lane & 15;
  // T1 remap (nwg % 8 == 0 at all call sites): logical n-fastest.
  const int nwg = gridDim.x * gridDim.y;
  const int lin = blockIdx.x + gridDim.x * blockIdx.y;
  const int logical = (lin & 7) * (nwg >> 3) + (lin >> 3);
  const int nbn = gridDim.y;
  const int mb = logical / nbn, nb = logical - mb * nbn;
  const int m0 = mb * 256, n0 = nb * 128;
  const int wm = (wave >> 1) * 64, wn = (wave & 1) * 64;

  f32x4 acc[4][4];
#pragma unroll
  for (int i = 0; i < 4; ++i)
#pragma unroll
    for (int j = 0; j < 4; ++j) acc[i][j] = (f32x4){0.f, 0.f, 0.f, 0.f};

  auto stage = [&](int kc, int buf) {
    // A tile 256x32 = 1024 chunks (16 B), 2 per thread.
#pragma unroll
    for (int l = 0; l < 2; ++l) {
      int c = l * 512 + tid;
      int row = c >> 2, e8 = (c & 3) * 8;
      gl_lds16(&A[(size_t)(m0 + row) * lda + kc + e8], &As[buf][c * 8]);
    }
    // B tile 128x32 = 512 chunks, 1 per thread.
    {
      int row = tid >> 2, e8 = (tid & 3) * 8;
      gl_lds16(&BT[(size_t)(n0 + row) * K + kc + e8], &Bs[buf][tid * 8]);
    }
  };

  stage(0, 0);
  const int NI = K >> 5;
  for (int ki = 0; ki < NI; ++ki) {
    const int cur = ki & 1;
    __syncthreads();                     // vmcnt(0): tile ki staged; fences
                                         // prev-iter LDS readers of buf^1
    if (ki + 1 < NI) stage((ki + 1) << 5, cur ^ 1);
    bf16x8 af[4], bfr[4];
#pragma unroll
    for (int i = 0; i < 4; ++i) {
      af[i]  = *(const bf16x8*)&As[cur][(wm + i * 16 + r16) * 32 + quad * 8];
      bfr[i] = *(const bf16x8*)&Bs[cur][(wn + i * 16 + r16) * 32 + quad * 8];
    }
#pragma unroll
    for (int mi = 0; mi < 4; ++mi)
#pragma unroll
      for (int ni = 0; ni < 4; ++ni)
        acc[mi][ni] = mfma16(bfr[ni], af[mi], acc[mi][ni]);   // SWAPPED
  }

  // epilogue (swapped layout): row = m0+wm+mi*16+r16 (one row/lane),
  // cols = n0+wn+ni*16+quad*4+{0..3} (regs) -> vector stores.
#pragma unroll
  for (int mi = 0; mi < 4; ++mi) {
    const int row = m0 + wm + mi * 16 + r16;
#pragma unroll
    for (int ni = 0; ni < 4; ++ni) {
      const int col = n0 + wn + ni * 16 + quad * 4;
      float4 bv = bias ? *(const float4*)&bias[col]
                       : make_float4(0.f, 0.f, 0.f, 0.f);
      float v[4];
#pragma unroll
      for (int r = 0; r < 4; ++r) {
        float s = (col + r >= sc_lo && col + r < sc_hi) ? scv : 1.0f;
        v[r] = (acc[mi][ni][r] + (&bv.x)[r]) * s;
      }
      if (Cf) {
        *(float4*)&Cf[(size_t)row * ldc + coff + col] =
            make_float4(v[0], v[1], v[2], v[3]);
      } else {
        uint2 pk;
        pk.x = cvtpk_bf16(v[0], v[1]);
        pk.y = cvtpk_bf16(v[2], v[3]);
        *(uint2*)&Cb[(size_t)row * ldc + coff + col] = pk;
      }
    }
  }
}

// ---------------------------------------------------------------------------
// gemm_proj: steps 5+6 merged (R5); dbuf + swapped epilogue (R6/R7 version,
// kept: 512 blocks = 2/CU, under its 5-block LDS cap -> no tail here).
// ---------------------------------------------------------------------------
__global__ __launch_bounds__(256)
void gemm_proj(const ushort_t* __restrict__ rB,
               const ushort_t* __restrict__ hT, const ushort_t* __restrict__ lT,
               const float* __restrict__ hb, const float* __restrict__ lb,
               ushort_t* __restrict__ y)
{
  __shared__ __align__(16) ushort_t As[2][128 * 32];
  __shared__ __align__(16) ushort_t Bs[2][128 * 32];
  const int tid  = threadIdx.x;
  const int wave = tid >> 6, lane = tid & 63;
  const int quad = lane >> 4, r16 = lane & 15;
  // T1 remap, n-fastest (nwg = 512)
  const int lin = blockIdx.x + 128 * blockIdx.y;
  const int logical = (lin & 7) * 64 + (lin >> 3);
  const int nidx = logical & 3, m0 = (logical >> 2) * 128;
  const int sel = nidx >> 1, n0 = (nidx & 1) * 128;
  const ushort_t* A  = rB + sel * 256;
  const ushort_t* BT = sel ? lT : hT;
  const float* bias  = sel ? lb : hb;
  const int coff = sel * 256;
  const int wm = (wave >> 1) * 64, wn = (wave & 1) * 64;

  f32x4 acc[4][4];
#pragma unroll
  for (int i = 0; i < 4; ++i)
#pragma unroll
    for (int j = 0; j < 4; ++j) acc[i][j] = (f32x4){0.f, 0.f, 0.f, 0.f};

  auto stage = [&](int kc, int buf) {
#pragma unroll
    for (int p = 0; p < 4; ++p) {
      int wp = p * 4 + wave;
      int lc = ((wp & 7) << 6) + lane;
      int row = lc >> 2, e8 = (lc & 3) * 8;
      if (wp < 8) gl_lds16(&A[(size_t)(m0 + row) * 512 + kc + e8], &As[buf][lc * 8]);
      else        gl_lds16(&BT[(size_t)(n0 + row) * 256 + kc + e8], &Bs[buf][lc * 8]);
    }
  };

  stage(0, 0);
  for (int ki = 0; ki < 8; ++ki) {
    const int cur = ki & 1;
    __syncthreads();
    if (ki + 1 < 8) stage((ki + 1) << 5, cur ^ 1);
    bf16x8 af[4], bfr[4];
#pragma unroll
    for (int i = 0; i < 4; ++i) {
      af[i]  = *(const bf16x8*)&As[cur][(wm + i * 16 + r16) * 32 + quad * 8];
      bfr[i] = *(const bf16x8*)&Bs[cur][(wn + i * 16 + r16) * 32 + quad * 8];
    }
#pragma unroll
    for (int mi = 0; mi < 4; ++mi)
#pragma unroll
      for (int ni = 0; ni < 4; ++ni)
        acc[mi][ni] = mfma16(bfr[ni], af[mi], acc[mi][ni]);   // SWAPPED
  }

#pragma unroll
  for (int mi = 0; mi < 4; ++mi) {
    const int row = m0 + wm + mi * 16 + r16;
#pragma unroll
    for (int ni = 0; ni < 4; ++ni) {
      const int col = n0 + wn + ni * 16 + quad * 4;
      float4 bv = *(const float4*)&bias[col];
      uint2 pk;
      pk.x = cvtpk_bf16(acc[mi][ni][0] + bv.x, acc[mi][ni][1] + bv.y);
      pk.y = cvtpk_bf16(acc[mi][ni][2] + bv.z, acc[mi][ni][3] + bv.w);
      *(uint2*)&y[(size_t)row * 512 + coff + col] = pk;
    }
  }
}

// ---------------------------------------------------------------------------
// Flash attention v10b: QG independent 32-query groups per wave (templated).
// (unchanged from R5 -- see that round's notes.)
// ---------------------------------------------------------------------------
template<int QG>
__global__ __launch_bounds__(256, 2)
void flash_attn9(const ushort_t* __restrict__ Q, int qs, int q_ch,
                 const ushort_t* __restrict__ Kg, int ks, int k_ch,
                 const ushort_t* __restrict__ vT,
                 ushort_t* __restrict__ O, int os, int o_ch,
                 int N)
{
  // [buf][64 rows][64 bf16] ; K rows = keys (cols d), V rows = d (cols keys)
  __shared__ __align__(16) ushort_t Ks[2][64 * 64];
  __shared__ __align__(16) ushort_t Vs[2][64 * 64];

  const int H = gridDim.y;
  const int tid = threadIdx.x, wave = tid >> 6, lane = tid & 63;
  const int c = lane & 31, hh = lane >> 5;

  // T1: chunked XCD remap (bijective; nwg % 8 == 0).
  const int nwg = gridDim.x * H * gridDim.z;
  const int lin = blockIdx.x + gridDim.x * (blockIdx.y + H * blockIdx.z);
  const int logical = (lin & 7) * (nwg >> 3) + (lin >> 3);
  const int QBS = 8 / QG;                  // q-blocks per (b,h)
  const int qb = logical & (QBS - 1);
  const int t8 = logical / QBS;
  const int b = (H == 8) ? (t8 >> 3) : (t8 >> 2);
  const int h = t8 - b * H;
  const int q0 = qb * (128 * QG) + wave * (32 * QG);

  // Q fragments: B-operand layout B[k=d][n=query]: lane (hh,c) holds
  // query q0+qg*32+c, d = s*16 + hh*8 + j -> qf[qg][s] at byte-col s*16+hh*8.
  bf16x8 qf[QG][4];
#pragma unroll
  for (int qg = 0; qg < QG; ++qg) {
    const ushort_t* qp =
        Q + ((size_t)b * N + q0 + qg * 32 + c) * qs + q_ch + h * 64 + hh * 8;
#pragma unroll
    for (int s = 0; s < 4; ++s) qf[qg][s] = *(const bf16x8*)&qp[s * 16];
  }
  const ushort_t* kbase = Kg + ((size_t)b * N) * ks + k_ch + h * 64;
  const ushort_t* vbase = vT + ((size_t)(b * H + h) * 64) * N;

  f32x16 oacc[QG][2];
#pragma unroll
  for (int qg = 0; qg < QG; ++qg)
#pragma unroll
    for (int i = 0; i < 16; ++i) { oacc[qg][0][i] = 0.f; oacc[qg][1][i] = 0.f; }
  float l_acc[QG];
#pragma unroll
  for (int qg = 0; qg < QG; ++qg) l_acc[qg] = 0.f;

  auto stage = [&](int s0, int buf) {
#pragma unroll
    for (int p = 0; p < 4; ++p) {
      int wp = p * 4 + wave;                 // 0..15: 0..7 -> K, 8..15 -> V
      int lc = ((wp & 7) << 6) + lane;       // chunk 0..511 within tile
      int row = lc >> 3, cc = lc & 7;
      int e8 = ((cc ^ (row & 7)) * 8);       // inverse-swizzled SOURCE chunk
      if (wp < 8) gl_lds16(kbase + (size_t)(s0 + row) * ks + e8, &Ks[buf][lc * 8]);
      else        gl_lds16(vbase + (size_t)row * N + s0 + e8,    &Vs[buf][lc * 8]);
    }
  };

  stage(0, 0);
  const int NT = N >> 6;
  for (int it = 0; it < NT; ++it) {
    const int cur = it & 1;
    __syncthreads();                     // vmcnt(0) drain: tile `it` staged;
                                         // also fences prev-iter LDS readers
    if (it + 1 < NT) stage((it + 1) << 6, cur ^ 1);

    bf16x8 Bf[QG][4];                    // PV B-operand, k-steps of 16 keys
#pragma unroll
    for (int kb = 0; kb < 2; ++kb) {
      // K fragments shared across the QG query groups.
      const int krow = kb * 32 + c;
      const ushort_t* kr = &Ks[cur][krow * 64];
      bf16x8 kf[4];
#pragma unroll
      for (int s = 0; s < 4; ++s)
        kf[s] = *(const bf16x8*)&kr[(((s << 1) + hh) ^ (krow & 7)) * 8];

#pragma unroll
      for (int qg = 0; qg < QG; ++qg) {
        // S^T block: A = K rows (m = key kb*32 + (lane&31)), B = Q[qg].
        f32x16 z;
#pragma unroll
        for (int i = 0; i < 16; ++i) z[i] = 0.f;
#pragma unroll
        for (int s = 0; s < 4; ++s) z = mfma32(kf[s], qf[qg][s], z);
        // exp + pack: reg r <-> key kb*32 + (r&3) + 8*(r>>2) + 4*hh
        float ts = 0.f;
        unsigned W[8];
#pragma unroll
        for (int t = 0; t < 8; ++t) {
          float p0 = __builtin_amdgcn_exp2f(z[2 * t]);
          float p1 = __builtin_amdgcn_exp2f(z[2 * t + 1]);
          ts += p0 + p1;
          W[t] = cvtpk_bf16(p0, p1);
        }
        l_acc[qg] += ts;
        // B[k=hh*8+j][n=c] per k-step, element i = keys {s*16+hh*8+2i, +1}:
        //  u0=[W0_lo|W2_lo] u1=[W1_lo|W3_lo] u2=[W0_hi|W2_hi] u3=[W1_hi|W3_hi]
        // swap(a,b): a=[a_lo|b_lo], b=[a_hi|b_hi] -> swap(W0,W2)=(u0,u2),
        // swap(W1,W3)=(u1,u3); W4..W7 for the second k-step.  [verified R4]
        union U8 { bf16x8 f; unsigned u[4]; } f0, f1;
        unsigned a0 = W[0], b0 = W[2]; pl32swap(a0, b0);
        unsigned a1 = W[1], b1 = W[3]; pl32swap(a1, b1);
        f0.u[0] = a0; f0.u[1] = a1; f0.u[2] = b0; f0.u[3] = b1;
        unsigned a2 = W[4], b2 = W[6]; pl32swap(a2, b2);
        unsigned a3 = W[5], b3 = W[7]; pl32swap(a3, b3);
        f1.u[0] = a2; f1.u[1] = a3; f1.u[2] = b2; f1.u[3] = b3;
        Bf[qg][kb * 2]     = f0.f;
        Bf[qg][kb * 2 + 1] = f1.f;
      }
    }

    // PV: O^T = mfma32(A = V^T (m = d), B = P), k-steps of 16 keys; V
    // fragments shared across query groups.
#pragma unroll
    for (int db = 0; db < 2; ++db) {
      const int vrow = db * 32 + c;
      const ushort_t* vr = &Vs[cur][vrow * 64];
      bf16x8 vf[4];
#pragma unroll
      for (int s = 0; s < 4; ++s)
        vf[s] = *(const bf16x8*)&vr[(((s << 1) + hh) ^ (vrow & 7)) * 8];
#pragma unroll
      for (int qg = 0; qg < QG; ++qg)
#pragma unroll
        for (int s = 0; s < 4; ++s)
          oacc[qg][db] = mfma32(vf[s], Bf[qg][s], oacc[qg][db]);
    }
  }

  // epilogue: l(query c) = l_acc(h0) + l_acc(h1); O^T reg r of dblk db is
  // d = db*32 + (r&3) + 8*(r>>2) + 4*hh, query = c.
#pragma unroll
  for (int qg = 0; qg < QG; ++qg) {
    float l = l_acc[qg] + __shfl_xor(l_acc[qg], 32);
    float inv = 1.f / l;
    ushort_t* op = O + ((size_t)b * N + q0 + qg * 32 + c) * os + o_ch + h * 64;
#pragma unroll
    for (int db = 0; db < 2; ++db) {
#pragma unroll
      for (int g = 0; g < 4; ++g) {
        uint2 pkv;
        pkv.x = cvtpk_bf16(oacc[qg][db][4 * g + 0] * inv, oacc[qg][db][4 * g + 1] * inv);
        pkv.y = cvtpk_bf16(oacc[qg][db][4 * g + 2] * inv, oacc[qg][db][4 * g + 3] * inv);
        *(uint2*)&op[db * 32 + g * 8 + hh * 4] = pkv;
      }
    }
  }
}

// ---------------------------------------------------------------------------
// V transpose: in [B*N][ld] bf16 (channel ch, head h) -> out [B*H][64][N]
// ---------------------------------------------------------------------------
__global__ __launch_bounds__(256)
void transpose_v(const ushort_t* __restrict__ in, int ld, int ch,
                 ushort_t* __restrict__ out, int N, int H)
{
  __shared__ __align__(16) ushort_t T[64][72];
  const int s0 = blockIdx.x * 64, h = blockIdx.y, b = blockIdx.z;
  const int tid = threadIdx.x;
#pragma unroll
  for (int p = 0; p < 2; ++p) {
    int c = p * 256 + tid;
    int sr = c >> 3, d0 = (c & 7) * 8;
    *(uint4*)&T[sr][d0] =
        *(const uint4*)&in[((size_t)b * N + s0 + sr) * ld + ch + h * 64 + d0];
  }
  __syncthreads();
  const int d = tid >> 2, sp = (tid & 3) * 16;
  union { uint4 v; ushort_t u[8]; } A, B;
#pragma unroll
  for (int j = 0; j < 8; ++j) { A.u[j] = T[sp + j][d]; B.u[j] = T[sp + 8 + j][d]; }
  ushort_t* op = out + ((size_t)(b * H + h) * 64 + d) * N + s0 + sp;
  *(uint4*)&op[0] = A.v;
  *(uint4*)&op[8] = B.v;
}

// ---------------------------------------------------------------------------
// hifi window attention (2x2 windows, 4 heads). qkv rows stride ld; per-token
// layout [3][4 heads][64]. Output stride 512, cols 0..255.
// (q here is NOT pre-scaled by the GEMM; keeps its own 0.125 + __expf.)
// ---------------------------------------------------------------------------
__global__ __launch_bounds__(256)
void hifi_win(const ushort_t* __restrict__ qkv, int ld, ushort_t* __restrict__ out)
{
  const int bg = blockIdx.x;
  const int b = bg >> 8, g = bg & 255;
  const int head = threadIdx.x >> 6, lane = threadIdx.x & 63;
  const int gh = g >> 4, gw = g & 15;

  int n[4];
  float q[4], k[4], v[4];
#pragma unroll
  for (int t = 0; t < 4; ++t) {
    n[t] = (gh * 2 + (t >> 1)) * 32 + gw * 2 + (t & 1);
    size_t base = ((size_t)b * 1024 + n[t]) * ld + head * 64 + lane;
    q[t] = bf2f(qkv[base]);
    k[t] = bf2f(qkv[base + 256]);
    v[t] = bf2f(qkv[base + 512]);
  }
  float sc[4][4];
#pragma unroll
  for (int t = 0; t < 4; ++t)
#pragma unroll
    for (int s = 0; s < 4; ++s) {
      float p = q[t] * k[s];
#pragma unroll
      for (int off = 32; off >= 1; off >>= 1) p += __shfl_xor(p, off);
      sc[t][s] = p * 0.125f;
    }
#pragma unroll
  for (int t = 0; t < 4; ++t) {
    float m = fmaxf(fmaxf(sc[t][0], sc[t][1]), fmaxf(sc[t][2], sc[t][3]));
    float p0 = __expf(sc[t][0] - m), p1 = __expf(sc[t][1] - m);
    float p2 = __expf(sc[t][2] - m), p3 = __expf(sc[t][3] - m);
    float sum = p0 + p1 + p2 + p3;
    float o = (p0 * v[0] + p1 * v[1] + p2 * v[2] + p3 * v[3]) / sum;
    out[((size_t)b * 1024 + n[t]) * 512 + head * 64 + lane] = f2bf(o);
  }
}

// ---------------------------------------------------------------------------
// Merged weight prep: 7 transposes W[K][N] fp32 -> WT[N][K] bf16 in one launch.
// ---------------------------------------------------------------------------
struct WEnt { const float* W; ushort_t* WT; int K; int N; };
struct WArgs { WEnt e[7]; };

__global__ __launch_bounds__(256)
void w_prep(WArgs a)
{
  WEnt w = a.e[blockIdx.z];
  if ((int)blockIdx.x >= (w.K >> 6) || (int)blockIdx.y >= (w.N >> 6)) return;
  __shared__ float T[64][65];
  const int k0 = blockIdx.x * 64, n0 = blockIdx.y * 64;
  const int tid = threadIdx.x;
#pragma unroll
  for (int p = 0; p < 4; ++p) {
    int c = p * 256 + tid;
    int kr = c >> 4, f4 = (c & 15) * 4;
    float4 v = *(const float4*)&w.W[(size_t)(k0 + kr) * w.N + n0 + f4];
    T[f4 + 0][kr] = v.x; T[f4 + 1][kr] = v.y;
    T[f4 + 2][kr] = v.z; T[f4 + 3][kr] = v.w;
  }
  __syncthreads();
  const int nl = tid >> 2, kp = (tid & 3) * 16;
  union { uint4 v; ushort_t u[8]; } A, B;
#pragma unroll
  for (int j = 0; j < 8; ++j) {
    A.u[j] = f2bf(T[nl][kp + j]);
    B.u[j] = f2bf(T[nl][kp + 8 + j]);
  }
  ushort_t* op = w.WT + (size_t)(n0 + nl) * w.K + k0 + kp;
  *(uint4*)&op[0] = A.v;
  *(uint4*)&op[8] = B.v;
}

// xpe = bf16(x + pos_emb), vectorized x4
__global__ void add_pos(const float* __restrict__ x, const float* __restrict__ pos,
                        ushort_t* __restrict__ xpe)
{
  int idx = blockIdx.x * 256 + threadIdx.x;
  int e = idx * 4;
  float4 xv = *(const float4*)&x[e];
  float4 pv = *(const float4*)&pos[e & (512 * 1024 - 1)];
  uint2 pk;
  pk.x = pk_bf16(xv.x + pv.x, xv.y + pv.y);
  pk.y = pk_bf16(xv.z + pv.z, xv.w + pv.w);
  *(uint2*)&xpe[e] = pk;
}

extern "C" void kernel_launch(void* const* d_in, const int* in_sizes, int n_in,
                              void* d_out, int out_size, void* d_ws, size_t ws_size,
                              hipStream_t stream)
{
  const float* x         = (const float*)d_in[0];
  const float* pos       = (const float*)d_in[1];
  const float* l_q_w     = (const float*)d_in[2];
  const float* l_kv_w    = (const float*)d_in[3];
  const float* l_proj_w  = (const float*)d_in[4];
  const float* l_proj_b  = (const float*)d_in[5];
  const float* h_qkv_w   = (const float*)d_in[6];
  const float* h_proj_w  = (const float*)d_in[7];
  const float* h_proj_b  = (const float*)d_in[8];
  const float* in_proj_w = (const float*)d_in[9];
  const float* in_proj_b = (const float*)d_in[10];
  const float* out_proj_w= (const float*)d_in[11];
  const float* out_proj_b= (const float*)d_in[12];
  float* out = (float*)d_out;

  // 0.125 * log2(e): flash_attn uses exp2 directly.
  const float QSCALE = 0.125f * 1.44269504f;

  char* ws = (char*)d_ws;
  ushort_t* xpe = (ushort_t*)(ws);                       // 16 MB @ 0
  ushort_t* y   = (ushort_t*)(ws + (size_t)16777216);    // 16 MB @ 16M
  ushort_t* F   = (ushort_t*)(ws + (size_t)33554432);    // 48 MB @ 32M (fused acts)
  ushort_t* rB  = (ushort_t*)(ws + (size_t)83886080);    // 16 MB @ 80M
  ushort_t* wb  = (ushort_t*)(ws + (size_t)100663296);   // ~4 MB @ 96M (weights)

  // fused BT for the xpe GEMM: rows [0,768)=h_qkv, [768,1024)=l_q, [1024,1536)=l_kv
  ushort_t* F_T      = wb;                        // 1536 x 512
  ushort_t* h_projT  = wb + 786432;               // 256 x 256
  ushort_t* l_projT  = wb + 851968;               // 256 x 256
  ushort_t* in_projT = wb + 917504;               // 1536 x 512
  ushort_t* out_projT= wb + 1703936;              // 512 x 512

  const int M = 16384;
  ushort_t* vT_lo = xpe;   // 8 MB; xpe dead after fused GEMM
  ushort_t* vT_m  = rB;    // 16 MB; rB dead after lproj

  WArgs wa;
  wa.e[0] = {h_qkv_w,   F_T,                 512, 768};
  wa.e[1] = {l_q_w,     F_T + 768 * 512,     512, 256};
  wa.e[2] = {l_kv_w,    F_T + 1024 * 512,    512, 512};
  wa.e[3] = {h_proj_w,  h_projT,             256, 256};
  wa.e[4] = {l_proj_w,  l_projT,             256, 256};
  wa.e[5] = {in_proj_w, in_projT,            512, 1536};
  wa.e[6] = {out_proj_w,out_projT,           512, 512};
  w_prep<<<dim3(8, 24, 7), dim3(256), 0, stream>>>(wa);

  add_pos<<<dim3(8192), dim3(256), 0, stream>>>(x, pos, xpe);

  // 1. fused qkv GEMM: [M,512] x [512,1536] -> F (lofi q cols pre-scaled)
  //    256x128 tiles: grid 64x12 = 768 blocks = exactly 3/CU (no tail)
  gemm_bt<<<dim3(M / 256, 12), dim3(512), 0, stream>>>(
      xpe, 512, F_T, nullptr, F, nullptr, 1536, 0, 512, QSCALE, 768, 1024);
  // 2. hifi window attention -> rB cols [0,256)
  hifi_win<<<dim3(4096), dim3(256), 0, stream>>>(F, 1536, rB);
  // 3. transpose lofi V (F cols 1280..1535) -> vT_lo (xpe region, now dead)
  transpose_v<<<dim3(16, 4, 16), dim3(256), 0, stream>>>(
      F, 1536, 1280, vT_lo, 1024, 4);
  // 4. lofi attention (4 heads) -> rB cols [256,512)   (QG=1: 512 blocks)
  flash_attn9<1><<<dim3(8, 4, 16), dim3(256), 0, stream>>>(
      F, 1536, 768, F, 1536, 1024, vT_lo, rB, 512, 256, 1024);
  // 5+6. hifi & lofi proj merged -> y  (512 blocks = 2/CU)
  gemm_proj<<<dim3(128, 4), dim3(256), 0, stream>>>(
      rB, h_projT, l_projT, h_proj_b, l_proj_b, y);
  // 7. mha qkv: [M,512] x [512,1536] -> F (q cols pre-scaled)
  gemm_bt<<<dim3(M / 256, 12), dim3(512), 0, stream>>>(
      y, 512, in_projT, in_proj_b, F, nullptr, 1536, 0, 512, QSCALE, 0, 512);
  // 8. transpose mha V (F cols 1024..1535) -> vT_m (rB dead now)
  transpose_v<<<dim3(16, 8, 16), dim3(256), 0, stream>>>(
      F, 1536, 1024, vT_m, 1024, 8);
  // 9. mha attention (8 heads) -> xpe region [M,512]  (QG=2: 64 q/wave,
  //    512 blocks = 2/CU; two independent chains per wave)
  flash_attn9<2><<<dim3(4, 8, 16), dim3(256), 0, stream>>>(
      F, 1536, 0, F, 1536, 512, vT_m, xpe, 512, 0, 1024);
  // 10. out proj -> d_out fp32 (grid 64x4 = 256 blocks = 1/CU exact)
  gemm_bt<<<dim3(M / 256, 4), dim3(512), 0, stream>>>(
      xpe, 512, out_projT, out_proj_b, nullptr, out, 512, 0, 512, 1.0f, 0, 0);
}

// Round 10
// 326.768 us; speedup vs baseline: 1.6847x; 1.0220x over previous
//
#include <hip/hip_runtime.h>

typedef unsigned short ushort_t;
typedef short bf16x8 __attribute__((ext_vector_type(8)));
typedef float f32x4 __attribute__((ext_vector_type(4)));
typedef float f32x16 __attribute__((ext_vector_type(16)));

#define DEV __device__ __forceinline__

// round-half-up bf16 (2 ops)
DEV ushort_t f2bf(float f) {
  return (ushort_t)((__float_as_uint(f) + 0x8000u) >> 16);
}
// pack two floats -> 2 bf16 in one u32 (3 ops: add, add, v_perm_b32)
DEV unsigned pk_bf16(float lo, float hi) {
  unsigned a = __float_as_uint(lo) + 0x8000u;
  unsigned b = __float_as_uint(hi) + 0x8000u;
  return __builtin_amdgcn_perm(b, a, 0x07060302);  // {b.hi16, a.hi16}
}
// single-op packed cvt (RNE): lo16 = bf16(lo), hi16 = bf16(hi).
DEV unsigned cvtpk_bf16(float lo, float hi) {
  unsigned r;
  asm("v_cvt_pk_bf16_f32 %0, %1, %2" : "=v"(r) : "v"(lo), "v"(hi));
  return r;
}
DEV float bf2f(ushort_t h) {
  union { unsigned int u; float f; } v; v.u = ((unsigned int)h) << 16;
  return v.f;
}
DEV f32x4 mfma16(bf16x8 a, bf16x8 b, f32x4 c) {
  return __builtin_amdgcn_mfma_f32_16x16x32_bf16(a, b, c, 0, 0, 0);
}
DEV f32x16 mfma32(bf16x8 a, bf16x8 b, f32x16 c) {
  return __builtin_amdgcn_mfma_f32_32x32x16_bf16(a, b, c, 0, 0, 0);
}
// v_permlane32_swap_b32 (gfx950, verified R4):
// after pl32swap(a,b): a = [a_lo | b_lo], b = [a_hi | b_hi]  ([lo|hi] halves).
DEV void pl32swap(unsigned &a, unsigned &b) {
  asm("v_permlane32_swap_b32 %0, %1" : "+v"(a), "+v"(b));
}
typedef __attribute__((address_space(3))) void lds_void;
typedef const __attribute__((address_space(1))) void glb_void;
DEV void gl_lds16(const void* g, void* l) {
  __builtin_amdgcn_global_load_lds((glb_void*)g, (lds_void*)l, 16, 0, 0);
}

// ---------------------------------------------------------------------------
// bf16 GEMM (R6-measured-best structure + isolated vector epilogue):
// C = A[M,K] * BT[N,K]^T (+bias, +col-scale window). 128x128 tile, 4 waves,
// 4x4 MFMA, 16 KB single-buffered LDS, 2 barriers/iter -> ~6 blocks/CU.
// R7/R8/R9 lesson: EVERY variant that cut blocks/CU lost (8-phase 1/CU: +4us;
// dbuf 5/CU: +4; 256x128 3/CU: +5) -- at K=512 (16 iters) inter-block TLP
// hides staging latency better than any intra-block pipeline expressed here.
// Residency is the binding resource; do not trade it for schedule.
// This round's single isolated change (residency-neutral): SWAPPED-OPERAND
// MFMA acc = mfma16(bfr, af) -> C/D layout gives output row on lane&15 and
// 4 CONSECUTIVE cols in regs -> uint2/float4 stores (16 instead of 64 store
// instrs/thread, 16 cvtpk instead of 128 f2bf VALU ops), float4 bias loads.
// Epilogue math correctness-proven in R9 (passed, absmax 1e-3).
// T1 XCD remap (R5): m-major within XCD chunk keeps A slice + B panel
// L2-resident (FETCH ~20 MB).
// ---------------------------------------------------------------------------
__global__ __launch_bounds__(256)
void gemm_bt(const ushort_t* __restrict__ A, int lda,
             const ushort_t* __restrict__ BT,
             const float* __restrict__ bias,
             ushort_t* __restrict__ Cb, float* __restrict__ Cf,
             int ldc, int coff, int K, float scv, int sc_lo, int sc_hi)
{
  __shared__ __align__(16) ushort_t As[128 * 32];
  __shared__ __align__(16) ushort_t Bs[128 * 32];
  const int tid  = threadIdx.x;
  const int wave = tid >> 6, lane = tid & 63;
  const int quad = lane >> 4, r16 = lane & 15;
  // T1 remap (nwg % 8 == 0 for all call sites): logical n-fastest.
  const int nwg = gridDim.x * gridDim.y;
  const int lin = blockIdx.x + gridDim.x * blockIdx.y;
  const int logical = (lin & 7) * (nwg >> 3) + (lin >> 3);
  const int nbn = gridDim.y;
  const int mb = logical / nbn, nb = logical - mb * nbn;
  const int m0 = mb * 128, n0 = nb * 128;
  const int wm = (wave >> 1) * 64, wn = (wave & 1) * 64;

  f32x4 acc[4][4];
#pragma unroll
  for (int i = 0; i < 4; ++i)
#pragma unroll
    for (int j = 0; j < 4; ++j) acc[i][j] = (f32x4){0.f, 0.f, 0.f, 0.f};

  for (int kc = 0; kc < K; kc += 32) {
#pragma unroll
    for (int p = 0; p < 4; ++p) {
      int wp = p * 4 + wave;                 // 0..15; 0..7 -> As, 8..15 -> Bs
      int lc = ((wp & 7) << 6) + lane;       // chunk 0..511 within array
      int row = lc >> 2, e8 = (lc & 3) * 8;
      if (wp < 8) gl_lds16(&A[(size_t)(m0 + row) * lda + kc + e8], &As[lc * 8]);
      else        gl_lds16(&BT[(size_t)(n0 + row) * K  + kc + e8], &Bs[lc * 8]);
    }
    __syncthreads();
    bf16x8 af[4], bfr[4];
#pragma unroll
    for (int i = 0; i < 4; ++i) {
      af[i]  = *(const bf16x8*)&As[(wm + i * 16 + r16) * 32 + quad * 8];
      bfr[i] = *(const bf16x8*)&Bs[(wn + i * 16 + r16) * 32 + quad * 8];
    }
#pragma unroll
    for (int mi = 0; mi < 4; ++mi)
#pragma unroll
      for (int ni = 0; ni < 4; ++ni)
        acc[mi][ni] = mfma16(bfr[ni], af[mi], acc[mi][ni]);   // SWAPPED
    __syncthreads();
  }

  // epilogue (swapped layout): row = m0+wm+mi*16+r16 (one row/lane),
  // cols = n0+wn+ni*16+quad*4+{0..3} (regs) -> vector stores.
#pragma unroll
  for (int mi = 0; mi < 4; ++mi) {
    const int row = m0 + wm + mi * 16 + r16;
#pragma unroll
    for (int ni = 0; ni < 4; ++ni) {
      const int col = n0 + wn + ni * 16 + quad * 4;
      float4 bv = bias ? *(const float4*)&bias[col]
                       : make_float4(0.f, 0.f, 0.f, 0.f);
      float v[4];
#pragma unroll
      for (int r = 0; r < 4; ++r) {
        float s = (col + r >= sc_lo && col + r < sc_hi) ? scv : 1.0f;
        v[r] = (acc[mi][ni][r] + (&bv.x)[r]) * s;
      }
      if (Cf) {
        *(float4*)&Cf[(size_t)row * ldc + coff + col] =
            make_float4(v[0], v[1], v[2], v[3]);
      } else {
        uint2 pk;
        pk.x = cvtpk_bf16(v[0], v[1]);
        pk.y = cvtpk_bf16(v[2], v[3]);
        *(uint2*)&Cb[(size_t)row * ldc + coff + col] = pk;
      }
    }
  }
}

// ---------------------------------------------------------------------------
// gemm_proj: steps 5+6 merged into ONE launch (R5). R6-measured version
// (single-buffer, 2 barriers) kept verbatim -- part of the 313.7 config.
// ---------------------------------------------------------------------------
__global__ __launch_bounds__(256)
void gemm_proj(const ushort_t* __restrict__ rB,
               const ushort_t* __restrict__ hT, const ushort_t* __restrict__ lT,
               const float* __restrict__ hb, const float* __restrict__ lb,
               ushort_t* __restrict__ y)
{
  __shared__ __align__(16) ushort_t As[128 * 32];
  __shared__ __align__(16) ushort_t Bs[128 * 32];
  const int tid  = threadIdx.x;
  const int wave = tid >> 6, lane = tid & 63;
  const int quad = lane >> 4, r16 = lane & 15;
  // T1 remap, n-fastest (nwg = 512)
  const int lin = blockIdx.x + 128 * blockIdx.y;
  const int logical = (lin & 7) * 64 + (lin >> 3);
  const int nidx = logical & 3, m0 = (logical >> 2) * 128;
  const int sel = nidx >> 1, n0 = (nidx & 1) * 128;
  const ushort_t* A  = rB + sel * 256;
  const ushort_t* BT = sel ? lT : hT;
  const float* bias  = sel ? lb : hb;
  const int coff = sel * 256;
  const int wm = (wave >> 1) * 64, wn = (wave & 1) * 64;

  f32x4 acc[4][4];
#pragma unroll
  for (int i = 0; i < 4; ++i)
#pragma unroll
    for (int j = 0; j < 4; ++j) acc[i][j] = (f32x4){0.f, 0.f, 0.f, 0.f};

  for (int kc = 0; kc < 256; kc += 32) {
#pragma unroll
    for (int p = 0; p < 4; ++p) {
      int wp = p * 4 + wave;
      int lc = ((wp & 7) << 6) + lane;
      int row = lc >> 2, e8 = (lc & 3) * 8;
      if (wp < 8) gl_lds16(&A[(size_t)(m0 + row) * 512 + kc + e8], &As[lc * 8]);
      else        gl_lds16(&BT[(size_t)(n0 + row) * 256 + kc + e8], &Bs[lc * 8]);
    }
    __syncthreads();
    bf16x8 af[4], bfr[4];
#pragma unroll
    for (int i = 0; i < 4; ++i) {
      af[i]  = *(const bf16x8*)&As[(wm + i * 16 + r16) * 32 + quad * 8];
      bfr[i] = *(const bf16x8*)&Bs[(wn + i * 16 + r16) * 32 + quad * 8];
    }
#pragma unroll
    for (int mi = 0; mi < 4; ++mi)
#pragma unroll
      for (int ni = 0; ni < 4; ++ni)
        acc[mi][ni] = mfma16(af[mi], bfr[ni], acc[mi][ni]);
    __syncthreads();
  }

#pragma unroll
  for (int mi = 0; mi < 4; ++mi) {
#pragma unroll
    for (int ni = 0; ni < 4; ++ni) {
      int col = n0 + wn + ni * 16 + r16;
      float bv = bias[col];
#pragma unroll
      for (int r = 0; r < 4; ++r) {
        int row = m0 + wm + mi * 16 + quad * 4 + r;
        y[(size_t)row * 512 + coff + col] = f2bf(acc[mi][ni][r] + bv);
      }
    }
  }
}

// ---------------------------------------------------------------------------
// Flash attention v10b: QG independent 32-query groups per wave (templated).
// (unchanged since R5 -- measured 46.8 us mha / ~31 lofi.)
// ---------------------------------------------------------------------------
template<int QG>
__global__ __launch_bounds__(256, 2)
void flash_attn9(const ushort_t* __restrict__ Q, int qs, int q_ch,
                 const ushort_t* __restrict__ Kg, int ks, int k_ch,
                 const ushort_t* __restrict__ vT,
                 ushort_t* __restrict__ O, int os, int o_ch,
                 int N)
{
  // [buf][64 rows][64 bf16] ; K rows = keys (cols d), V rows = d (cols keys)
  __shared__ __align__(16) ushort_t Ks[2][64 * 64];
  __shared__ __align__(16) ushort_t Vs[2][64 * 64];

  const int H = gridDim.y;
  const int tid = threadIdx.x, wave = tid >> 6, lane = tid & 63;
  const int c = lane & 31, hh = lane >> 5;

  // T1: chunked XCD remap (bijective; nwg % 8 == 0).
  const int nwg = gridDim.x * H * gridDim.z;
  const int lin = blockIdx.x + gridDim.x * (blockIdx.y + H * blockIdx.z);
  const int logical = (lin & 7) * (nwg >> 3) + (lin >> 3);
  const int QBS = 8 / QG;                  // q-blocks per (b,h)
  const int qb = logical & (QBS - 1);
  const int t8 = logical / QBS;
  const int b = (H == 8) ? (t8 >> 3) : (t8 >> 2);
  const int h = t8 - b * H;
  const int q0 = qb * (128 * QG) + wave * (32 * QG);

  // Q fragments: B-operand layout B[k=d][n=query]: lane (hh,c) holds
  // query q0+qg*32+c, d = s*16 + hh*8 + j -> qf[qg][s] at byte-col s*16+hh*8.
  bf16x8 qf[QG][4];
#pragma unroll
  for (int qg = 0; qg < QG; ++qg) {
    const ushort_t* qp =
        Q + ((size_t)b * N + q0 + qg * 32 + c) * qs + q_ch + h * 64 + hh * 8;
#pragma unroll
    for (int s = 0; s < 4; ++s) qf[qg][s] = *(const bf16x8*)&qp[s * 16];
  }
  const ushort_t* kbase = Kg + ((size_t)b * N) * ks + k_ch + h * 64;
  const ushort_t* vbase = vT + ((size_t)(b * H + h) * 64) * N;

  f32x16 oacc[QG][2];
#pragma unroll
  for (int qg = 0; qg < QG; ++qg)
#pragma unroll
    for (int i = 0; i < 16; ++i) { oacc[qg][0][i] = 0.f; oacc[qg][1][i] = 0.f; }
  float l_acc[QG];
#pragma unroll
  for (int qg = 0; qg < QG; ++qg) l_acc[qg] = 0.f;

  auto stage = [&](int s0, int buf) {
#pragma unroll
    for (int p = 0; p < 4; ++p) {
      int wp = p * 4 + wave;                 // 0..15: 0..7 -> K, 8..15 -> V
      int lc = ((wp & 7) << 6) + lane;       // chunk 0..511 within tile
      int row = lc >> 3, cc = lc & 7;
      int e8 = ((cc ^ (row & 7)) * 8);       // inverse-swizzled SOURCE chunk
      if (wp < 8) gl_lds16(kbase + (size_t)(s0 + row) * ks + e8, &Ks[buf][lc * 8]);
      else        gl_lds16(vbase + (size_t)row * N + s0 + e8,    &Vs[buf][lc * 8]);
    }
  };

  stage(0, 0);
  const int NT = N >> 6;
  for (int it = 0; it < NT; ++it) {
    const int cur = it & 1;
    __syncthreads();                     // vmcnt(0) drain: tile `it` staged;
                                         // also fences prev-iter LDS readers
    if (it + 1 < NT) stage((it + 1) << 6, cur ^ 1);

    bf16x8 Bf[QG][4];                    // PV B-operand, k-steps of 16 keys
#pragma unroll
    for (int kb = 0; kb < 2; ++kb) {
      // K fragments shared across the QG query groups.
      const int krow = kb * 32 + c;
      const ushort_t* kr = &Ks[cur][krow * 64];
      bf16x8 kf[4];
#pragma unroll
      for (int s = 0; s < 4; ++s)
        kf[s] = *(const bf16x8*)&kr[(((s << 1) + hh) ^ (krow & 7)) * 8];

#pragma unroll
      for (int qg = 0; qg < QG; ++qg) {
        // S^T block: A = K rows (m = key kb*32 + (lane&31)), B = Q[qg].
        f32x16 z;
#pragma unroll
        for (int i = 0; i < 16; ++i) z[i] = 0.f;
#pragma unroll
        for (int s = 0; s < 4; ++s) z = mfma32(kf[s], qf[qg][s], z);
        // exp + pack: reg r <-> key kb*32 + (r&3) + 8*(r>>2) + 4*hh
        float ts = 0.f;
        unsigned W[8];
#pragma unroll
        for (int t = 0; t < 8; ++t) {
          float p0 = __builtin_amdgcn_exp2f(z[2 * t]);
          float p1 = __builtin_amdgcn_exp2f(z[2 * t + 1]);
          ts += p0 + p1;
          W[t] = cvtpk_bf16(p0, p1);
        }
        l_acc[qg] += ts;
        // B[k=hh*8+j][n=c] per k-step, element i = keys {s*16+hh*8+2i, +1}:
        //  u0=[W0_lo|W2_lo] u1=[W1_lo|W3_lo] u2=[W0_hi|W2_hi] u3=[W1_hi|W3_hi]
        // swap(a,b): a=[a_lo|b_lo], b=[a_hi|b_hi] -> swap(W0,W2)=(u0,u2),
        // swap(W1,W3)=(u1,u3); W4..W7 for the second k-step.  [verified R4]
        union U8 { bf16x8 f; unsigned u[4]; } f0, f1;
        unsigned a0 = W[0], b0 = W[2]; pl32swap(a0, b0);
        unsigned a1 = W[1], b1 = W[3]; pl32swap(a1, b1);
        f0.u[0] = a0; f0.u[1] = a1; f0.u[2] = b0; f0.u[3] = b1;
        unsigned a2 = W[4], b2 = W[6]; pl32swap(a2, b2);
        unsigned a3 = W[5], b3 = W[7]; pl32swap(a3, b3);
        f1.u[0] = a2; f1.u[1] = a3; f1.u[2] = b2; f1.u[3] = b3;
        Bf[qg][kb * 2]     = f0.f;
        Bf[qg][kb * 2 + 1] = f1.f;
      }
    }

    // PV: O^T = mfma32(A = V^T (m = d), B = P), k-steps of 16 keys; V
    // fragments shared across query groups.
#pragma unroll
    for (int db = 0; db < 2; ++db) {
      const int vrow = db * 32 + c;
      const ushort_t* vr = &Vs[cur][vrow * 64];
      bf16x8 vf[4];
#pragma unroll
      for (int s = 0; s < 4; ++s)
        vf[s] = *(const bf16x8*)&vr[(((s << 1) + hh) ^ (vrow & 7)) * 8];
#pragma unroll
      for (int qg = 0; qg < QG; ++qg)
#pragma unroll
        for (int s = 0; s < 4; ++s)
          oacc[qg][db] = mfma32(vf[s], Bf[qg][s], oacc[qg][db]);
    }
  }

  // epilogue: l(query c) = l_acc(h0) + l_acc(h1); O^T reg r of dblk db is
  // d = db*32 + (r&3) + 8*(r>>2) + 4*hh, query = c.
#pragma unroll
  for (int qg = 0; qg < QG; ++qg) {
    float l = l_acc[qg] + __shfl_xor(l_acc[qg], 32);
    float inv = 1.f / l;
    ushort_t* op = O + ((size_t)b * N + q0 + qg * 32 + c) * os + o_ch + h * 64;
#pragma unroll
    for (int db = 0; db < 2; ++db) {
#pragma unroll
      for (int g = 0; g < 4; ++g) {
        uint2 pkv;
        pkv.x = cvtpk_bf16(oacc[qg][db][4 * g + 0] * inv, oacc[qg][db][4 * g + 1] * inv);
        pkv.y = cvtpk_bf16(oacc[qg][db][4 * g + 2] * inv, oacc[qg][db][4 * g + 3] * inv);
        *(uint2*)&op[db * 32 + g * 8 + hh * 4] = pkv;
      }
    }
  }
}

// ---------------------------------------------------------------------------
// V transpose: in [B*N][ld] bf16 (channel ch, head h) -> out [B*H][64][N]
// ---------------------------------------------------------------------------
__global__ __launch_bounds__(256)
void transpose_v(const ushort_t* __restrict__ in, int ld, int ch,
                 ushort_t* __restrict__ out, int N, int H)
{
  __shared__ __align__(16) ushort_t T[64][72];
  const int s0 = blockIdx.x * 64, h = blockIdx.y, b = blockIdx.z;
  const int tid = threadIdx.x;
#pragma unroll
  for (int p = 0; p < 2; ++p) {
    int c = p * 256 + tid;
    int sr = c >> 3, d0 = (c & 7) * 8;
    *(uint4*)&T[sr][d0] =
        *(const uint4*)&in[((size_t)b * N + s0 + sr) * ld + ch + h * 64 + d0];
  }
  __syncthreads();
  const int d = tid >> 2, sp = (tid & 3) * 16;
  union { uint4 v; ushort_t u[8]; } A, B;
#pragma unroll
  for (int j = 0; j < 8; ++j) { A.u[j] = T[sp + j][d]; B.u[j] = T[sp + 8 + j][d]; }
  ushort_t* op = out + ((size_t)(b * H + h) * 64 + d) * N + s0 + sp;
  *(uint4*)&op[0] = A.v;
  *(uint4*)&op[8] = B.v;
}

// ---------------------------------------------------------------------------
// hifi window attention (2x2 windows, 4 heads). qkv rows stride ld; per-token
// layout [3][4 heads][64]. Output stride 512, cols 0..255.
// (q here is NOT pre-scaled by the GEMM; keeps its own 0.125 + __expf.)
// ---------------------------------------------------------------------------
__global__ __launch_bounds__(256)
void hifi_win(const ushort_t* __restrict__ qkv, int ld, ushort_t* __restrict__ out)
{
  const int bg = blockIdx.x;
  const int b = bg >> 8, g = bg & 255;
  const int head = threadIdx.x >> 6, lane = threadIdx.x & 63;
  const int gh = g >> 4, gw = g & 15;

  int n[4];
  float q[4], k[4], v[4];
#pragma unroll
  for (int t = 0; t < 4; ++t) {
    n[t] = (gh * 2 + (t >> 1)) * 32 + gw * 2 + (t & 1);
    size_t base = ((size_t)b * 1024 + n[t]) * ld + head * 64 + lane;
    q[t] = bf2f(qkv[base]);
    k[t] = bf2f(qkv[base + 256]);
    v[t] = bf2f(qkv[base + 512]);
  }
  float sc[4][4];
#pragma unroll
  for (int t = 0; t < 4; ++t)
#pragma unroll
    for (int s = 0; s < 4; ++s) {
      float p = q[t] * k[s];
#pragma unroll
      for (int off = 32; off >= 1; off >>= 1) p += __shfl_xor(p, off);
      sc[t][s] = p * 0.125f;
    }
#pragma unroll
  for (int t = 0; t < 4; ++t) {
    float m = fmaxf(fmaxf(sc[t][0], sc[t][1]), fmaxf(sc[t][2], sc[t][3]));
    float p0 = __expf(sc[t][0] - m), p1 = __expf(sc[t][1] - m);
    float p2 = __expf(sc[t][2] - m), p3 = __expf(sc[t][3] - m);
    float sum = p0 + p1 + p2 + p3;
    float o = (p0 * v[0] + p1 * v[1] + p2 * v[2] + p3 * v[3]) / sum;
    out[((size_t)b * 1024 + n[t]) * 512 + head * 64 + lane] = f2bf(o);
  }
}

// ---------------------------------------------------------------------------
// Merged weight prep: 7 transposes W[K][N] fp32 -> WT[N][K] bf16 in one launch.
// ---------------------------------------------------------------------------
struct WEnt { const float* W; ushort_t* WT; int K; int N; };
struct WArgs { WEnt e[7]; };

__global__ __launch_bounds__(256)
void w_prep(WArgs a)
{
  WEnt w = a.e[blockIdx.z];
  if ((int)blockIdx.x >= (w.K >> 6) || (int)blockIdx.y >= (w.N >> 6)) return;
  __shared__ float T[64][65];
  const int k0 = blockIdx.x * 64, n0 = blockIdx.y * 64;
  const int tid = threadIdx.x;
#pragma unroll
  for (int p = 0; p < 4; ++p) {
    int c = p * 256 + tid;
    int kr = c >> 4, f4 = (c & 15) * 4;
    float4 v = *(const float4*)&w.W[(size_t)(k0 + kr) * w.N + n0 + f4];
    T[f4 + 0][kr] = v.x; T[f4 + 1][kr] = v.y;
    T[f4 + 2][kr] = v.z; T[f4 + 3][kr] = v.w;
  }
  __syncthreads();
  const int nl = tid >> 2, kp = (tid & 3) * 16;
  union { uint4 v; ushort_t u[8]; } A, B;
#pragma unroll
  for (int j = 0; j < 8; ++j) {
    A.u[j] = f2bf(T[nl][kp + j]);
    B.u[j] = f2bf(T[nl][kp + 8 + j]);
  }
  ushort_t* op = w.WT + (size_t)(n0 + nl) * w.K + k0 + kp;
  *(uint4*)&op[0] = A.v;
  *(uint4*)&op[8] = B.v;
}

// xpe = bf16(x + pos_emb), vectorized x4
__global__ void add_pos(const float* __restrict__ x, const float* __restrict__ pos,
                        ushort_t* __restrict__ xpe)
{
  int idx = blockIdx.x * 256 + threadIdx.x;
  int e = idx * 4;
  float4 xv = *(const float4*)&x[e];
  float4 pv = *(const float4*)&pos[e & (512 * 1024 - 1)];
  uint2 pk;
  pk.x = pk_bf16(xv.x + pv.x, xv.y + pv.y);
  pk.y = pk_bf16(xv.z + pv.z, xv.w + pv.w);
  *(uint2*)&xpe[e] = pk;
}

extern "C" void kernel_launch(void* const* d_in, const int* in_sizes, int n_in,
                              void* d_out, int out_size, void* d_ws, size_t ws_size,
                              hipStream_t stream)
{
  const float* x         = (const float*)d_in[0];
  const float* pos       = (const float*)d_in[1];
  const float* l_q_w     = (const float*)d_in[2];
  const float* l_kv_w    = (const float*)d_in[3];
  const float* l_proj_w  = (const float*)d_in[4];
  const float* l_proj_b  = (const float*)d_in[5];
  const float* h_qkv_w   = (const float*)d_in[6];
  const float* h_proj_w  = (const float*)d_in[7];
  const float* h_proj_b  = (const float*)d_in[8];
  const float* in_proj_w = (const float*)d_in[9];
  const float* in_proj_b = (const float*)d_in[10];
  const float* out_proj_w= (const float*)d_in[11];
  const float* out_proj_b= (const float*)d_in[12];
  float* out = (float*)d_out;

  // 0.125 * log2(e): flash_attn uses exp2 directly.
  const float QSCALE = 0.125f * 1.44269504f;

  char* ws = (char*)d_ws;
  ushort_t* xpe = (ushort_t*)(ws);                       // 16 MB @ 0
  ushort_t* y   = (ushort_t*)(ws + (size_t)16777216);    // 16 MB @ 16M
  ushort_t* F   = (ushort_t*)(ws + (size_t)33554432);    // 48 MB @ 32M (fused acts)
  ushort_t* rB  = (ushort_t*)(ws + (size_t)83886080);    // 16 MB @ 80M
  ushort_t* wb  = (ushort_t*)(ws + (size_t)100663296);   // ~4 MB @ 96M (weights)

  // fused BT for the xpe GEMM: rows [0,768)=h_qkv, [768,1024)=l_q, [1024,1536)=l_kv
  ushort_t* F_T      = wb;                        // 1536 x 512
  ushort_t* h_projT  = wb + 786432;               // 256 x 256
  ushort_t* l_projT  = wb + 851968;               // 256 x 256
  ushort_t* in_projT = wb + 917504;               // 1536 x 512
  ushort_t* out_projT= wb + 1703936;              // 512 x 512

  const int M = 16384;
  ushort_t* vT_lo = xpe;   // 8 MB; xpe dead after fused GEMM
  ushort_t* vT_m  = rB;    // 16 MB; rB dead after lproj

  WArgs wa;
  wa.e[0] = {h_qkv_w,   F_T,                 512, 768};
  wa.e[1] = {l_q_w,     F_T + 768 * 512,     512, 256};
  wa.e[2] = {l_kv_w,    F_T + 1024 * 512,    512, 512};
  wa.e[3] = {h_proj_w,  h_projT,             256, 256};
  wa.e[4] = {l_proj_w,  l_projT,             256, 256};
  wa.e[5] = {in_proj_w, in_projT,            512, 1536};
  wa.e[6] = {out_proj_w,out_projT,           512, 512};
  w_prep<<<dim3(8, 24, 7), dim3(256), 0, stream>>>(wa);

  add_pos<<<dim3(8192), dim3(256), 0, stream>>>(x, pos, xpe);

  // 1. fused qkv GEMM: [M,512] x [512,1536] -> F (lofi q cols pre-scaled)
  gemm_bt<<<dim3(M / 128, 12), dim3(256), 0, stream>>>(
      xpe, 512, F_T, nullptr, F, nullptr, 1536, 0, 512, QSCALE, 768, 1024);
  // 2. hifi window attention -> rB cols [0,256)
  hifi_win<<<dim3(4096), dim3(256), 0, stream>>>(F, 1536, rB);
  // 3. transpose lofi V (F cols 1280..1535) -> vT_lo (xpe region, now dead)
  transpose_v<<<dim3(16, 4, 16), dim3(256), 0, stream>>>(
      F, 1536, 1280, vT_lo, 1024, 4);
  // 4. lofi attention (4 heads) -> rB cols [256,512)   (QG=1: 512 blocks)
  flash_attn9<1><<<dim3(8, 4, 16), dim3(256), 0, stream>>>(
      F, 1536, 768, F, 1536, 1024, vT_lo, rB, 512, 256, 1024);
  // 5+6. hifi & lofi proj merged -> y  (512 blocks = 2/CU)
  gemm_proj<<<dim3(128, 4), dim3(256), 0, stream>>>(
      rB, h_projT, l_projT, h_proj_b, l_proj_b, y);
  // 7. mha qkv: [M,512] x [512,1536] -> F (q cols pre-scaled)
  gemm_bt<<<dim3(M / 128, 12), dim3(256), 0, stream>>>(
      y, 512, in_projT, in_proj_b, F, nullptr, 1536, 0, 512, QSCALE, 0, 512);
  // 8. transpose mha V (F cols 1024..1535) -> vT_m (rB dead now)
  transpose_v<<<dim3(16, 8, 16), dim3(256), 0, stream>>>(
      F, 1536, 1024, vT_m, 1024, 8);
  // 9. mha attention (8 heads) -> xpe region [M,512]  (QG=2: 64 q/wave,
  //    512 blocks = 2/CU; two independent chains per wave)
  flash_attn9<2><<<dim3(4, 8, 16), dim3(256), 0, stream>>>(
      F, 1536, 0, F, 1536, 512, vT_m, xpe, 512, 0, 1024);
  // 10. out proj -> d_out fp32
  gemm_bt<<<dim3(M / 128, 4), dim3(256), 0, stream>>>(
      xpe, 512, out_projT, out_proj_b, nullptr, out, 512, 0, 512, 1.0f, 0, 0);
}

// Round 11
// 314.867 us; speedup vs baseline: 1.7484x; 1.0378x over previous
//
#include <hip/hip_runtime.h>

typedef unsigned short ushort_t;
typedef short bf16x8 __attribute__((ext_vector_type(8)));
typedef float f32x4 __attribute__((ext_vector_type(4)));
typedef float f32x16 __attribute__((ext_vector_type(16)));

#define DEV __device__ __forceinline__

// round-half-up bf16 (2 ops)
DEV ushort_t f2bf(float f) {
  return (ushort_t)((__float_as_uint(f) + 0x8000u) >> 16);
}
// pack two floats -> 2 bf16 in one u32 (3 ops: add, add, v_perm_b32)
DEV unsigned pk_bf16(float lo, float hi) {
  unsigned a = __float_as_uint(lo) + 0x8000u;
  unsigned b = __float_as_uint(hi) + 0x8000u;
  return __builtin_amdgcn_perm(b, a, 0x07060302);  // {b.hi16, a.hi16}
}
// single-op packed cvt (RNE): lo16 = bf16(lo), hi16 = bf16(hi).
DEV unsigned cvtpk_bf16(float lo, float hi) {
  unsigned r;
  asm("v_cvt_pk_bf16_f32 %0, %1, %2" : "=v"(r) : "v"(lo), "v"(hi));
  return r;
}
DEV float bf2f(ushort_t h) {
  union { unsigned int u; float f; } v; v.u = ((unsigned int)h) << 16;
  return v.f;
}
DEV f32x4 mfma16(bf16x8 a, bf16x8 b, f32x4 c) {
  return __builtin_amdgcn_mfma_f32_16x16x32_bf16(a, b, c, 0, 0, 0);
}
DEV f32x16 mfma32(bf16x8 a, bf16x8 b, f32x16 c) {
  return __builtin_amdgcn_mfma_f32_32x32x16_bf16(a, b, c, 0, 0, 0);
}
// v_permlane32_swap_b32 (gfx950, verified R4):
// after pl32swap(a,b): a = [a_lo | b_lo], b = [a_hi | b_hi]  ([lo|hi] halves).
DEV void pl32swap(unsigned &a, unsigned &b) {
  asm("v_permlane32_swap_b32 %0, %1" : "+v"(a), "+v"(b));
}
typedef __attribute__((address_space(3))) void lds_void;
typedef const __attribute__((address_space(1))) void glb_void;
DEV void gl_lds16(const void* g, void* l) {
  __builtin_amdgcn_global_load_lds((glb_void*)g, (lds_void*)l, 16, 0, 0);
}

// ---------------------------------------------------------------------------
// bf16 GEMM (R6-exact structure + issue-early staging):
// C = A[M,K] * BT[N,K]^T (+bias, +col-scale window). 128x128 tile, 4 waves,
// 4x4 MFMA, 16 KB single-buffered LDS, 2 barriers/iter, ~6 blocks/CU exact.
// R10 lesson: swapped-operand vector epilogue LOST (strided 8B lane stores,
// 16 segments/inst vs 4) -- reverted to R6 scalar epilogue (46 us measured).
// R7-R9 lesson: any residency cut loses; 6 blocks/CU is binding.
// THIS round's single change (residency-neutral): loop reordered from
//   {stage(k); barrier; ds_read+mfma; barrier}
// to
//   {barrier; ds_read; barrier; stage(k+1) -> SAME buffer; mfma}
// After barrier#2 every wave's fragments are in REGISTERS (MFMA has no LDS
// dependency), so next-tile staging can overwrite the buffer and fly across
// the MFMA block; barrier#1 of iter k+1 drains it. Same barriers, same LDS,
// same occupancy -- only the issue point moves (flash-proven principle).
// T1 XCD remap (R5): m-major within XCD chunk keeps A slice + B panel
// L2-resident (FETCH ~20 MB).
// ---------------------------------------------------------------------------
__global__ __launch_bounds__(256)
void gemm_bt(const ushort_t* __restrict__ A, int lda,
             const ushort_t* __restrict__ BT,
             const float* __restrict__ bias,
             ushort_t* __restrict__ Cb, float* __restrict__ Cf,
             int ldc, int coff, int K, float scv, int sc_lo, int sc_hi)
{
  __shared__ __align__(16) ushort_t As[128 * 32];
  __shared__ __align__(16) ushort_t Bs[128 * 32];
  const int tid  = threadIdx.x;
  const int wave = tid >> 6, lane = tid & 63;
  const int quad = lane >> 4, r16 = lane & 15;
  // T1 remap (nwg % 8 == 0 for all call sites): logical n-fastest.
  const int nwg = gridDim.x * gridDim.y;
  const int lin = blockIdx.x + gridDim.x * blockIdx.y;
  const int logical = (lin & 7) * (nwg >> 3) + (lin >> 3);
  const int nbn = gridDim.y;
  const int mb = logical / nbn, nb = logical - mb * nbn;
  const int m0 = mb * 128, n0 = nb * 128;
  const int wm = (wave >> 1) * 64, wn = (wave & 1) * 64;

  f32x4 acc[4][4];
#pragma unroll
  for (int i = 0; i < 4; ++i)
#pragma unroll
    for (int j = 0; j < 4; ++j) acc[i][j] = (f32x4){0.f, 0.f, 0.f, 0.f};

  auto stage = [&](int kc) {
#pragma unroll
    for (int p = 0; p < 4; ++p) {
      int wp = p * 4 + wave;                 // 0..15; 0..7 -> As, 8..15 -> Bs
      int lc = ((wp & 7) << 6) + lane;       // chunk 0..511 within array
      int row = lc >> 2, e8 = (lc & 3) * 8;
      if (wp < 8) gl_lds16(&A[(size_t)(m0 + row) * lda + kc + e8], &As[lc * 8]);
      else        gl_lds16(&BT[(size_t)(n0 + row) * K  + kc + e8], &Bs[lc * 8]);
    }
  };

  stage(0);
  const int NI = K >> 5;
  for (int ki = 0; ki < NI; ++ki) {
    __syncthreads();                 // drains stage(ki): tile ki in LDS
    bf16x8 af[4], bfr[4];
#pragma unroll
    for (int i = 0; i < 4; ++i) {
      af[i]  = *(const bf16x8*)&As[(wm + i * 16 + r16) * 32 + quad * 8];
      bfr[i] = *(const bf16x8*)&Bs[(wn + i * 16 + r16) * 32 + quad * 8];
    }
    __syncthreads();                 // all waves' fragments in registers;
                                     // buffer free for overwrite
    if (ki + 1 < NI) stage((ki + 1) << 5);   // flies across the MFMAs
#pragma unroll
    for (int mi = 0; mi < 4; ++mi)
#pragma unroll
      for (int ni = 0; ni < 4; ++ni)
        acc[mi][ni] = mfma16(af[mi], bfr[ni], acc[mi][ni]);
  }

  // C/D layout: col = lane&15, row = quad*4 + reg  [m89/m91] (R6 epilogue)
#pragma unroll
  for (int mi = 0; mi < 4; ++mi) {
#pragma unroll
    for (int ni = 0; ni < 4; ++ni) {
      int col = n0 + wn + ni * 16 + r16;
      float bv = bias ? bias[col] : 0.f;
      float s = (col >= sc_lo && col < sc_hi) ? scv : 1.0f;
#pragma unroll
      for (int r = 0; r < 4; ++r) {
        int row = m0 + wm + mi * 16 + quad * 4 + r;
        float v = (acc[mi][ni][r] + bv) * s;
        if (Cf) Cf[(size_t)row * ldc + coff + col] = v;
        else    Cb[(size_t)row * ldc + coff + col] = f2bf(v);
      }
    }
  }
}

// ---------------------------------------------------------------------------
// gemm_proj: steps 5+6 merged into ONE launch (R5). R6-measured version kept
// verbatim as control (single-buffer, 2 barriers; part of the 313.7 config).
// ---------------------------------------------------------------------------
__global__ __launch_bounds__(256)
void gemm_proj(const ushort_t* __restrict__ rB,
               const ushort_t* __restrict__ hT, const ushort_t* __restrict__ lT,
               const float* __restrict__ hb, const float* __restrict__ lb,
               ushort_t* __restrict__ y)
{
  __shared__ __align__(16) ushort_t As[128 * 32];
  __shared__ __align__(16) ushort_t Bs[128 * 32];
  const int tid  = threadIdx.x;
  const int wave = tid >> 6, lane = tid & 63;
  const int quad = lane >> 4, r16 = lane & 15;
  // T1 remap, n-fastest (nwg = 512)
  const int lin = blockIdx.x + 128 * blockIdx.y;
  const int logical = (lin & 7) * 64 + (lin >> 3);
  const int nidx = logical & 3, m0 = (logical >> 2) * 128;
  const int sel = nidx >> 1, n0 = (nidx & 1) * 128;
  const ushort_t* A  = rB + sel * 256;
  const ushort_t* BT = sel ? lT : hT;
  const float* bias  = sel ? lb : hb;
  const int coff = sel * 256;
  const int wm = (wave >> 1) * 64, wn = (wave & 1) * 64;

  f32x4 acc[4][4];
#pragma unroll
  for (int i = 0; i < 4; ++i)
#pragma unroll
    for (int j = 0; j < 4; ++j) acc[i][j] = (f32x4){0.f, 0.f, 0.f, 0.f};

  for (int kc = 0; kc < 256; kc += 32) {
#pragma unroll
    for (int p = 0; p < 4; ++p) {
      int wp = p * 4 + wave;
      int lc = ((wp & 7) << 6) + lane;
      int row = lc >> 2, e8 = (lc & 3) * 8;
      if (wp < 8) gl_lds16(&A[(size_t)(m0 + row) * 512 + kc + e8], &As[lc * 8]);
      else        gl_lds16(&BT[(size_t)(n0 + row) * 256 + kc + e8], &Bs[lc * 8]);
    }
    __syncthreads();
    bf16x8 af[4], bfr[4];
#pragma unroll
    for (int i = 0; i < 4; ++i) {
      af[i]  = *(const bf16x8*)&As[(wm + i * 16 + r16) * 32 + quad * 8];
      bfr[i] = *(const bf16x8*)&Bs[(wn + i * 16 + r16) * 32 + quad * 8];
    }
#pragma unroll
    for (int mi = 0; mi < 4; ++mi)
#pragma unroll
      for (int ni = 0; ni < 4; ++ni)
        acc[mi][ni] = mfma16(af[mi], bfr[ni], acc[mi][ni]);
    __syncthreads();
  }

#pragma unroll
  for (int mi = 0; mi < 4; ++mi) {
#pragma unroll
    for (int ni = 0; ni < 4; ++ni) {
      int col = n0 + wn + ni * 16 + r16;
      float bv = bias[col];
#pragma unroll
      for (int r = 0; r < 4; ++r) {
        int row = m0 + wm + mi * 16 + quad * 4 + r;
        y[(size_t)row * 512 + coff + col] = f2bf(acc[mi][ni][r] + bv);
      }
    }
  }
}

// ---------------------------------------------------------------------------
// Flash attention v10b: QG independent 32-query groups per wave (templated).
// (unchanged since R5 -- measured 46.8 us mha / ~31 lofi.)
// ---------------------------------------------------------------------------
template<int QG>
__global__ __launch_bounds__(256, 2)
void flash_attn9(const ushort_t* __restrict__ Q, int qs, int q_ch,
                 const ushort_t* __restrict__ Kg, int ks, int k_ch,
                 const ushort_t* __restrict__ vT,
                 ushort_t* __restrict__ O, int os, int o_ch,
                 int N)
{
  // [buf][64 rows][64 bf16] ; K rows = keys (cols d), V rows = d (cols keys)
  __shared__ __align__(16) ushort_t Ks[2][64 * 64];
  __shared__ __align__(16) ushort_t Vs[2][64 * 64];

  const int H = gridDim.y;
  const int tid = threadIdx.x, wave = tid >> 6, lane = tid & 63;
  const int c = lane & 31, hh = lane >> 5;

  // T1: chunked XCD remap (bijective; nwg % 8 == 0).
  const int nwg = gridDim.x * H * gridDim.z;
  const int lin = blockIdx.x + gridDim.x * (blockIdx.y + H * blockIdx.z);
  const int logical = (lin & 7) * (nwg >> 3) + (lin >> 3);
  const int QBS = 8 / QG;                  // q-blocks per (b,h)
  const int qb = logical & (QBS - 1);
  const int t8 = logical / QBS;
  const int b = (H == 8) ? (t8 >> 3) : (t8 >> 2);
  const int h = t8 - b * H;
  const int q0 = qb * (128 * QG) + wave * (32 * QG);

  // Q fragments: B-operand layout B[k=d][n=query]: lane (hh,c) holds
  // query q0+qg*32+c, d = s*16 + hh*8 + j -> qf[qg][s] at byte-col s*16+hh*8.
  bf16x8 qf[QG][4];
#pragma unroll
  for (int qg = 0; qg < QG; ++qg) {
    const ushort_t* qp =
        Q + ((size_t)b * N + q0 + qg * 32 + c) * qs + q_ch + h * 64 + hh * 8;
#pragma unroll
    for (int s = 0; s < 4; ++s) qf[qg][s] = *(const bf16x8*)&qp[s * 16];
  }
  const ushort_t* kbase = Kg + ((size_t)b * N) * ks + k_ch + h * 64;
  const ushort_t* vbase = vT + ((size_t)(b * H + h) * 64) * N;

  f32x16 oacc[QG][2];
#pragma unroll
  for (int qg = 0; qg < QG; ++qg)
#pragma unroll
    for (int i = 0; i < 16; ++i) { oacc[qg][0][i] = 0.f; oacc[qg][1][i] = 0.f; }
  float l_acc[QG];
#pragma unroll
  for (int qg = 0; qg < QG; ++qg) l_acc[qg] = 0.f;

  auto stage = [&](int s0, int buf) {
#pragma unroll
    for (int p = 0; p < 4; ++p) {
      int wp = p * 4 + wave;                 // 0..15: 0..7 -> K, 8..15 -> V
      int lc = ((wp & 7) << 6) + lane;       // chunk 0..511 within tile
      int row = lc >> 3, cc = lc & 7;
      int e8 = ((cc ^ (row & 7)) * 8);       // inverse-swizzled SOURCE chunk
      if (wp < 8) gl_lds16(kbase + (size_t)(s0 + row) * ks + e8, &Ks[buf][lc * 8]);
      else        gl_lds16(vbase + (size_t)row * N + s0 + e8,    &Vs[buf][lc * 8]);
    }
  };

  stage(0, 0);
  const int NT = N >> 6;
  for (int it = 0; it < NT; ++it) {
    const int cur = it & 1;
    __syncthreads();                     // vmcnt(0) drain: tile `it` staged;
                                         // also fences prev-iter LDS readers
    if (it + 1 < NT) stage((it + 1) << 6, cur ^ 1);

    bf16x8 Bf[QG][4];                    // PV B-operand, k-steps of 16 keys
#pragma unroll
    for (int kb = 0; kb < 2; ++kb) {
      // K fragments shared across the QG query groups.
      const int krow = kb * 32 + c;
      const ushort_t* kr = &Ks[cur][krow * 64];
      bf16x8 kf[4];
#pragma unroll
      for (int s = 0; s < 4; ++s)
        kf[s] = *(const bf16x8*)&kr[(((s << 1) + hh) ^ (krow & 7)) * 8];

#pragma unroll
      for (int qg = 0; qg < QG; ++qg) {
        // S^T block: A = K rows (m = key kb*32 + (lane&31)), B = Q[qg].
        f32x16 z;
#pragma unroll
        for (int i = 0; i < 16; ++i) z[i] = 0.f;
#pragma unroll
        for (int s = 0; s < 4; ++s) z = mfma32(kf[s], qf[qg][s], z);
        // exp + pack: reg r <-> key kb*32 + (r&3) + 8*(r>>2) + 4*hh
        float ts = 0.f;
        unsigned W[8];
#pragma unroll
        for (int t = 0; t < 8; ++t) {
          float p0 = __builtin_amdgcn_exp2f(z[2 * t]);
          float p1 = __builtin_amdgcn_exp2f(z[2 * t + 1]);
          ts += p0 + p1;
          W[t] = cvtpk_bf16(p0, p1);
        }
        l_acc[qg] += ts;
        // B[k=hh*8+j][n=c] per k-step, element i = keys {s*16+hh*8+2i, +1}:
        //  u0=[W0_lo|W2_lo] u1=[W1_lo|W3_lo] u2=[W0_hi|W2_hi] u3=[W1_hi|W3_hi]
        // swap(a,b): a=[a_lo|b_lo], b=[a_hi|b_hi] -> swap(W0,W2)=(u0,u2),
        // swap(W1,W3)=(u1,u3); W4..W7 for the second k-step.  [verified R4]
        union U8 { bf16x8 f; unsigned u[4]; } f0, f1;
        unsigned a0 = W[0], b0 = W[2]; pl32swap(a0, b0);
        unsigned a1 = W[1], b1 = W[3]; pl32swap(a1, b1);
        f0.u[0] = a0; f0.u[1] = a1; f0.u[2] = b0; f0.u[3] = b1;
        unsigned a2 = W[4], b2 = W[6]; pl32swap(a2, b2);
        unsigned a3 = W[5], b3 = W[7]; pl32swap(a3, b3);
        f1.u[0] = a2; f1.u[1] = a3; f1.u[2] = b2; f1.u[3] = b3;
        Bf[qg][kb * 2]     = f0.f;
        Bf[qg][kb * 2 + 1] = f1.f;
      }
    }

    // PV: O^T = mfma32(A = V^T (m = d), B = P), k-steps of 16 keys; V
    // fragments shared across query groups.
#pragma unroll
    for (int db = 0; db < 2; ++db) {
      const int vrow = db * 32 + c;
      const ushort_t* vr = &Vs[cur][vrow * 64];
      bf16x8 vf[4];
#pragma unroll
      for (int s = 0; s < 4; ++s)
        vf[s] = *(const bf16x8*)&vr[(((s << 1) + hh) ^ (vrow & 7)) * 8];
#pragma unroll
      for (int qg = 0; qg < QG; ++qg)
#pragma unroll
        for (int s = 0; s < 4; ++s)
          oacc[qg][db] = mfma32(vf[s], Bf[qg][s], oacc[qg][db]);
    }
  }

  // epilogue: l(query c) = l_acc(h0) + l_acc(h1); O^T reg r of dblk db is
  // d = db*32 + (r&3) + 8*(r>>2) + 4*hh, query = c.
#pragma unroll
  for (int qg = 0; qg < QG; ++qg) {
    float l = l_acc[qg] + __shfl_xor(l_acc[qg], 32);
    float inv = 1.f / l;
    ushort_t* op = O + ((size_t)b * N + q0 + qg * 32 + c) * os + o_ch + h * 64;
#pragma unroll
    for (int db = 0; db < 2; ++db) {
#pragma unroll
      for (int g = 0; g < 4; ++g) {
        uint2 pkv;
        pkv.x = cvtpk_bf16(oacc[qg][db][4 * g + 0] * inv, oacc[qg][db][4 * g + 1] * inv);
        pkv.y = cvtpk_bf16(oacc[qg][db][4 * g + 2] * inv, oacc[qg][db][4 * g + 3] * inv);
        *(uint2*)&op[db * 32 + g * 8 + hh * 4] = pkv;
      }
    }
  }
}

// ---------------------------------------------------------------------------
// V transpose: in [B*N][ld] bf16 (channel ch, head h) -> out [B*H][64][N]
// ---------------------------------------------------------------------------
__global__ __launch_bounds__(256)
void transpose_v(const ushort_t* __restrict__ in, int ld, int ch,
                 ushort_t* __restrict__ out, int N, int H)
{
  __shared__ __align__(16) ushort_t T[64][72];
  const int s0 = blockIdx.x * 64, h = blockIdx.y, b = blockIdx.z;
  const int tid = threadIdx.x;
#pragma unroll
  for (int p = 0; p < 2; ++p) {
    int c = p * 256 + tid;
    int sr = c >> 3, d0 = (c & 7) * 8;
    *(uint4*)&T[sr][d0] =
        *(const uint4*)&in[((size_t)b * N + s0 + sr) * ld + ch + h * 64 + d0];
  }
  __syncthreads();
  const int d = tid >> 2, sp = (tid & 3) * 16;
  union { uint4 v; ushort_t u[8]; } A, B;
#pragma unroll
  for (int j = 0; j < 8; ++j) { A.u[j] = T[sp + j][d]; B.u[j] = T[sp + 8 + j][d]; }
  ushort_t* op = out + ((size_t)(b * H + h) * 64 + d) * N + s0 + sp;
  *(uint4*)&op[0] = A.v;
  *(uint4*)&op[8] = B.v;
}

// ---------------------------------------------------------------------------
// hifi window attention (2x2 windows, 4 heads). qkv rows stride ld; per-token
// layout [3][4 heads][64]. Output stride 512, cols 0..255.
// (q here is NOT pre-scaled by the GEMM; keeps its own 0.125 + __expf.)
// ---------------------------------------------------------------------------
__global__ __launch_bounds__(256)
void hifi_win(const ushort_t* __restrict__ qkv, int ld, ushort_t* __restrict__ out)
{
  const int bg = blockIdx.x;
  const int b = bg >> 8, g = bg & 255;
  const int head = threadIdx.x >> 6, lane = threadIdx.x & 63;
  const int gh = g >> 4, gw = g & 15;

  int n[4];
  float q[4], k[4], v[4];
#pragma unroll
  for (int t = 0; t < 4; ++t) {
    n[t] = (gh * 2 + (t >> 1)) * 32 + gw * 2 + (t & 1);
    size_t base = ((size_t)b * 1024 + n[t]) * ld + head * 64 + lane;
    q[t] = bf2f(qkv[base]);
    k[t] = bf2f(qkv[base + 256]);
    v[t] = bf2f(qkv[base + 512]);
  }
  float sc[4][4];
#pragma unroll
  for (int t = 0; t < 4; ++t)
#pragma unroll
    for (int s = 0; s < 4; ++s) {
      float p = q[t] * k[s];
#pragma unroll
      for (int off = 32; off >= 1; off >>= 1) p += __shfl_xor(p, off);
      sc[t][s] = p * 0.125f;
    }
#pragma unroll
  for (int t = 0; t < 4; ++t) {
    float m = fmaxf(fmaxf(sc[t][0], sc[t][1]), fmaxf(sc[t][2], sc[t][3]));
    float p0 = __expf(sc[t][0] - m), p1 = __expf(sc[t][1] - m);
    float p2 = __expf(sc[t][2] - m), p3 = __expf(sc[t][3] - m);
    float sum = p0 + p1 + p2 + p3;
    float o = (p0 * v[0] + p1 * v[1] + p2 * v[2] + p3 * v[3]) / sum;
    out[((size_t)b * 1024 + n[t]) * 512 + head * 64 + lane] = f2bf(o);
  }
}

// ---------------------------------------------------------------------------
// Merged weight prep: 7 transposes W[K][N] fp32 -> WT[N][K] bf16 in one launch.
// ---------------------------------------------------------------------------
struct WEnt { const float* W; ushort_t* WT; int K; int N; };
struct WArgs { WEnt e[7]; };

__global__ __launch_bounds__(256)
void w_prep(WArgs a)
{
  WEnt w = a.e[blockIdx.z];
  if ((int)blockIdx.x >= (w.K >> 6) || (int)blockIdx.y >= (w.N >> 6)) return;
  __shared__ float T[64][65];
  const int k0 = blockIdx.x * 64, n0 = blockIdx.y * 64;
  const int tid = threadIdx.x;
#pragma unroll
  for (int p = 0; p < 4; ++p) {
    int c = p * 256 + tid;
    int kr = c >> 4, f4 = (c & 15) * 4;
    float4 v = *(const float4*)&w.W[(size_t)(k0 + kr) * w.N + n0 + f4];
    T[f4 + 0][kr] = v.x; T[f4 + 1][kr] = v.y;
    T[f4 + 2][kr] = v.z; T[f4 + 3][kr] = v.w;
  }
  __syncthreads();
  const int nl = tid >> 2, kp = (tid & 3) * 16;
  union { uint4 v; ushort_t u[8]; } A, B;
#pragma unroll
  for (int j = 0; j < 8; ++j) {
    A.u[j] = f2bf(T[nl][kp + j]);
    B.u[j] = f2bf(T[nl][kp + 8 + j]);
  }
  ushort_t* op = w.WT + (size_t)(n0 + nl) * w.K + k0 + kp;
  *(uint4*)&op[0] = A.v;
  *(uint4*)&op[8] = B.v;
}

// xpe = bf16(x + pos_emb), vectorized x4
__global__ void add_pos(const float* __restrict__ x, const float* __restrict__ pos,
                        ushort_t* __restrict__ xpe)
{
  int idx = blockIdx.x * 256 + threadIdx.x;
  int e = idx * 4;
  float4 xv = *(const float4*)&x[e];
  float4 pv = *(const float4*)&pos[e & (512 * 1024 - 1)];
  uint2 pk;
  pk.x = pk_bf16(xv.x + pv.x, xv.y + pv.y);
  pk.y = pk_bf16(xv.z + pv.z, xv.w + pv.w);
  *(uint2*)&xpe[e] = pk;
}

extern "C" void kernel_launch(void* const* d_in, const int* in_sizes, int n_in,
                              void* d_out, int out_size, void* d_ws, size_t ws_size,
                              hipStream_t stream)
{
  const float* x         = (const float*)d_in[0];
  const float* pos       = (const float*)d_in[1];
  const float* l_q_w     = (const float*)d_in[2];
  const float* l_kv_w    = (const float*)d_in[3];
  const float* l_proj_w  = (const float*)d_in[4];
  const float* l_proj_b  = (const float*)d_in[5];
  const float* h_qkv_w   = (const float*)d_in[6];
  const float* h_proj_w  = (const float*)d_in[7];
  const float* h_proj_b  = (const float*)d_in[8];
  const float* in_proj_w = (const float*)d_in[9];
  const float* in_proj_b = (const float*)d_in[10];
  const float* out_proj_w= (const float*)d_in[11];
  const float* out_proj_b= (const float*)d_in[12];
  float* out = (float*)d_out;

  // 0.125 * log2(e): flash_attn uses exp2 directly.
  const float QSCALE = 0.125f * 1.44269504f;

  char* ws = (char*)d_ws;
  ushort_t* xpe = (ushort_t*)(ws);                       // 16 MB @ 0
  ushort_t* y   = (ushort_t*)(ws + (size_t)16777216);    // 16 MB @ 16M
  ushort_t* F   = (ushort_t*)(ws + (size_t)33554432);    // 48 MB @ 32M (fused acts)
  ushort_t* rB  = (ushort_t*)(ws + (size_t)83886080);    // 16 MB @ 80M
  ushort_t* wb  = (ushort_t*)(ws + (size_t)100663296);   // ~4 MB @ 96M (weights)

  // fused BT for the xpe GEMM: rows [0,768)=h_qkv, [768,1024)=l_q, [1024,1536)=l_kv
  ushort_t* F_T      = wb;                        // 1536 x 512
  ushort_t* h_projT  = wb + 786432;               // 256 x 256
  ushort_t* l_projT  = wb + 851968;               // 256 x 256
  ushort_t* in_projT = wb + 917504;               // 1536 x 512
  ushort_t* out_projT= wb + 1703936;              // 512 x 512

  const int M = 16384;
  ushort_t* vT_lo = xpe;   // 8 MB; xpe dead after fused GEMM
  ushort_t* vT_m  = rB;    // 16 MB; rB dead after lproj

  WArgs wa;
  wa.e[0] = {h_qkv_w,   F_T,                 512, 768};
  wa.e[1] = {l_q_w,     F_T + 768 * 512,     512, 256};
  wa.e[2] = {l_kv_w,    F_T + 1024 * 512,    512, 512};
  wa.e[3] = {h_proj_w,  h_projT,             256, 256};
  wa.e[4] = {l_proj_w,  l_projT,             256, 256};
  wa.e[5] = {in_proj_w, in_projT,            512, 1536};
  wa.e[6] = {out_proj_w,out_projT,           512, 512};
  w_prep<<<dim3(8, 24, 7), dim3(256), 0, stream>>>(wa);

  add_pos<<<dim3(8192), dim3(256), 0, stream>>>(x, pos, xpe);

  // 1. fused qkv GEMM: [M,512] x [512,1536] -> F (lofi q cols pre-scaled)
  gemm_bt<<<dim3(M / 128, 12), dim3(256), 0, stream>>>(
      xpe, 512, F_T, nullptr, F, nullptr, 1536, 0, 512, QSCALE, 768, 1024);
  // 2. hifi window attention -> rB cols [0,256)
  hifi_win<<<dim3(4096), dim3(256), 0, stream>>>(F, 1536, rB);
  // 3. transpose lofi V (F cols 1280..1535) -> vT_lo (xpe region, now dead)
  transpose_v<<<dim3(16, 4, 16), dim3(256), 0, stream>>>(
      F, 1536, 1280, vT_lo, 1024, 4);
  // 4. lofi attention (4 heads) -> rB cols [256,512)   (QG=1: 512 blocks)
  flash_attn9<1><<<dim3(8, 4, 16), dim3(256), 0, stream>>>(
      F, 1536, 768, F, 1536, 1024, vT_lo, rB, 512, 256, 1024);
  // 5+6. hifi & lofi proj merged -> y  (512 blocks = 2/CU)
  gemm_proj<<<dim3(128, 4), dim3(256), 0, stream>>>(
      rB, h_projT, l_projT, h_proj_b, l_proj_b, y);
  // 7. mha qkv: [M,512] x [512,1536] -> F (q cols pre-scaled)
  gemm_bt<<<dim3(M / 128, 12), dim3(256), 0, stream>>>(
      y, 512, in_projT, in_proj_b, F, nullptr, 1536, 0, 512, QSCALE, 0, 512);
  // 8. transpose mha V (F cols 1024..1535) -> vT_m (rB dead now)
  transpose_v<<<dim3(16, 8, 16), dim3(256), 0, stream>>>(
      F, 1536, 1024, vT_m, 1024, 8);
  // 9. mha attention (8 heads) -> xpe region [M,512]  (QG=2: 64 q/wave,
  //    512 blocks = 2/CU; two independent chains per wave)
  flash_attn9<2><<<dim3(4, 8, 16), dim3(256), 0, stream>>>(
      F, 1536, 0, F, 1536, 512, vT_m, xpe, 512, 0, 1024);
  // 10. out proj -> d_out fp32
  gemm_bt<<<dim3(M / 128, 4), dim3(256), 0, stream>>>(
      xpe, 512, out_projT, out_proj_b, nullptr, out, 512, 0, 512, 1.0f, 0, 0);
}

// Round 12
// 310.949 us; speedup vs baseline: 1.7704x; 1.0126x over previous
//
#include <hip/hip_runtime.h>

typedef unsigned short ushort_t;
typedef short bf16x8 __attribute__((ext_vector_type(8)));
typedef float f32x4 __attribute__((ext_vector_type(4)));
typedef float f32x16 __attribute__((ext_vector_type(16)));

#define DEV __device__ __forceinline__

// round-half-up bf16 (2 ops)
DEV ushort_t f2bf(float f) {
  return (ushort_t)((__float_as_uint(f) + 0x8000u) >> 16);
}
// pack two floats -> 2 bf16 in one u32 (3 ops: add, add, v_perm_b32)
DEV unsigned pk_bf16(float lo, float hi) {
  unsigned a = __float_as_uint(lo) + 0x8000u;
  unsigned b = __float_as_uint(hi) + 0x8000u;
  return __builtin_amdgcn_perm(b, a, 0x07060302);  // {b.hi16, a.hi16}
}
// single-op packed cvt (RNE): lo16 = bf16(lo), hi16 = bf16(hi).
DEV unsigned cvtpk_bf16(float lo, float hi) {
  unsigned r;
  asm("v_cvt_pk_bf16_f32 %0, %1, %2" : "=v"(r) : "v"(lo), "v"(hi));
  return r;
}
DEV float bf2f(ushort_t h) {
  union { unsigned int u; float f; } v; v.u = ((unsigned int)h) << 16;
  return v.f;
}
DEV f32x4 mfma16(bf16x8 a, bf16x8 b, f32x4 c) {
  return __builtin_amdgcn_mfma_f32_16x16x32_bf16(a, b, c, 0, 0, 0);
}
DEV f32x16 mfma32(bf16x8 a, bf16x8 b, f32x16 c) {
  return __builtin_amdgcn_mfma_f32_32x32x16_bf16(a, b, c, 0, 0, 0);
}
// v_permlane32_swap_b32 (gfx950, verified R4):
// after pl32swap(a,b): a = [a_lo | b_lo], b = [a_hi | b_hi]  ([lo|hi] halves).
DEV void pl32swap(unsigned &a, unsigned &b) {
  asm("v_permlane32_swap_b32 %0, %1" : "+v"(a), "+v"(b));
}
typedef __attribute__((address_space(3))) void lds_void;
typedef const __attribute__((address_space(1))) void glb_void;
DEV void gl_lds16(const void* g, void* l) {
  __builtin_amdgcn_global_load_lds((glb_void*)g, (lds_void*)l, 16, 0, 0);
}

// ---------------------------------------------------------------------------
// bf16 GEMM (R11-measured-best: R6 structure + issue-early staging).
// C = A[M,K] * BT[N,K]^T (+bias, +col-scale window). 128x128 tile, 4 waves,
// 4x4 MFMA, 16 KB single-buffered LDS, 2 barriers/iter, ~6 blocks/CU.
// Loop: {barrier(drain stage ki); ds_read; barrier(frags in regs);
//        stage(ki+1) -> SAME buffer; mfma}  -- staging flies across MFMAs.
// R10: vector epilogue LOST (strided lane stores) -> R6 scalar epilogue.
// R7-R9: any residency cut loses; 6 blocks/CU binding.
// T1 XCD remap (R5): m-major within chunk; FETCH ~20 MB.
// ---------------------------------------------------------------------------
__global__ __launch_bounds__(256)
void gemm_bt(const ushort_t* __restrict__ A, int lda,
             const ushort_t* __restrict__ BT,
             const float* __restrict__ bias,
             ushort_t* __restrict__ Cb, float* __restrict__ Cf,
             int ldc, int coff, int K, float scv, int sc_lo, int sc_hi)
{
  __shared__ __align__(16) ushort_t As[128 * 32];
  __shared__ __align__(16) ushort_t Bs[128 * 32];
  const int tid  = threadIdx.x;
  const int wave = tid >> 6, lane = tid & 63;
  const int quad = lane >> 4, r16 = lane & 15;
  // T1 remap (nwg % 8 == 0 for all call sites): logical n-fastest.
  const int nwg = gridDim.x * gridDim.y;
  const int lin = blockIdx.x + gridDim.x * blockIdx.y;
  const int logical = (lin & 7) * (nwg >> 3) + (lin >> 3);
  const int nbn = gridDim.y;
  const int mb = logical / nbn, nb = logical - mb * nbn;
  const int m0 = mb * 128, n0 = nb * 128;
  const int wm = (wave >> 1) * 64, wn = (wave & 1) * 64;

  f32x4 acc[4][4];
#pragma unroll
  for (int i = 0; i < 4; ++i)
#pragma unroll
    for (int j = 0; j < 4; ++j) acc[i][j] = (f32x4){0.f, 0.f, 0.f, 0.f};

  auto stage = [&](int kc) {
#pragma unroll
    for (int p = 0; p < 4; ++p) {
      int wp = p * 4 + wave;                 // 0..15; 0..7 -> As, 8..15 -> Bs
      int lc = ((wp & 7) << 6) + lane;       // chunk 0..511 within array
      int row = lc >> 2, e8 = (lc & 3) * 8;
      if (wp < 8) gl_lds16(&A[(size_t)(m0 + row) * lda + kc + e8], &As[lc * 8]);
      else        gl_lds16(&BT[(size_t)(n0 + row) * K  + kc + e8], &Bs[lc * 8]);
    }
  };

  stage(0);
  const int NI = K >> 5;
  for (int ki = 0; ki < NI; ++ki) {
    __syncthreads();                 // drains stage(ki): tile ki in LDS
    bf16x8 af[4], bfr[4];
#pragma unroll
    for (int i = 0; i < 4; ++i) {
      af[i]  = *(const bf16x8*)&As[(wm + i * 16 + r16) * 32 + quad * 8];
      bfr[i] = *(const bf16x8*)&Bs[(wn + i * 16 + r16) * 32 + quad * 8];
    }
    __syncthreads();                 // all waves' fragments in registers;
                                     // buffer free for overwrite
    if (ki + 1 < NI) stage((ki + 1) << 5);   // flies across the MFMAs
#pragma unroll
    for (int mi = 0; mi < 4; ++mi)
#pragma unroll
      for (int ni = 0; ni < 4; ++ni)
        acc[mi][ni] = mfma16(af[mi], bfr[ni], acc[mi][ni]);
  }

  // C/D layout: col = lane&15, row = quad*4 + reg  [m89/m91] (R6 epilogue)
#pragma unroll
  for (int mi = 0; mi < 4; ++mi) {
#pragma unroll
    for (int ni = 0; ni < 4; ++ni) {
      int col = n0 + wn + ni * 16 + r16;
      float bv = bias ? bias[col] : 0.f;
      float s = (col >= sc_lo && col < sc_hi) ? scv : 1.0f;
#pragma unroll
      for (int r = 0; r < 4; ++r) {
        int row = m0 + wm + mi * 16 + quad * 4 + r;
        float v = (acc[mi][ni][r] + bv) * s;
        if (Cf) Cf[(size_t)row * ldc + coff + col] = v;
        else    Cb[(size_t)row * ldc + coff + col] = f2bf(v);
      }
    }
  }
}

// ---------------------------------------------------------------------------
// gemm_proj: steps 5+6 merged (R5). R12: issue-early staging reorder applied
// (exact pattern that won on gemm_bt in R11: barrier / ds_read / barrier /
// stage(k+1) same-buffer / mfma). Everything else R6-identical.
// ---------------------------------------------------------------------------
__global__ __launch_bounds__(256)
void gemm_proj(const ushort_t* __restrict__ rB,
               const ushort_t* __restrict__ hT, const ushort_t* __restrict__ lT,
               const float* __restrict__ hb, const float* __restrict__ lb,
               ushort_t* __restrict__ y)
{
  __shared__ __align__(16) ushort_t As[128 * 32];
  __shared__ __align__(16) ushort_t Bs[128 * 32];
  const int tid  = threadIdx.x;
  const int wave = tid >> 6, lane = tid & 63;
  const int quad = lane >> 4, r16 = lane & 15;
  // T1 remap, n-fastest (nwg = 512)
  const int lin = blockIdx.x + 128 * blockIdx.y;
  const int logical = (lin & 7) * 64 + (lin >> 3);
  const int nidx = logical & 3, m0 = (logical >> 2) * 128;
  const int sel = nidx >> 1, n0 = (nidx & 1) * 128;
  const ushort_t* A  = rB + sel * 256;
  const ushort_t* BT = sel ? lT : hT;
  const float* bias  = sel ? lb : hb;
  const int coff = sel * 256;
  const int wm = (wave >> 1) * 64, wn = (wave & 1) * 64;

  f32x4 acc[4][4];
#pragma unroll
  for (int i = 0; i < 4; ++i)
#pragma unroll
    for (int j = 0; j < 4; ++j) acc[i][j] = (f32x4){0.f, 0.f, 0.f, 0.f};

  auto stage = [&](int kc) {
#pragma unroll
    for (int p = 0; p < 4; ++p) {
      int wp = p * 4 + wave;
      int lc = ((wp & 7) << 6) + lane;
      int row = lc >> 2, e8 = (lc & 3) * 8;
      if (wp < 8) gl_lds16(&A[(size_t)(m0 + row) * 512 + kc + e8], &As[lc * 8]);
      else        gl_lds16(&BT[(size_t)(n0 + row) * 256 + kc + e8], &Bs[lc * 8]);
    }
  };

  stage(0);
  for (int ki = 0; ki < 8; ++ki) {
    __syncthreads();                 // drains stage(ki)
    bf16x8 af[4], bfr[4];
#pragma unroll
    for (int i = 0; i < 4; ++i) {
      af[i]  = *(const bf16x8*)&As[(wm + i * 16 + r16) * 32 + quad * 8];
      bfr[i] = *(const bf16x8*)&Bs[(wn + i * 16 + r16) * 32 + quad * 8];
    }
    __syncthreads();                 // fragments in registers
    if (ki + 1 < 8) stage((ki + 1) << 5);
#pragma unroll
    for (int mi = 0; mi < 4; ++mi)
#pragma unroll
      for (int ni = 0; ni < 4; ++ni)
        acc[mi][ni] = mfma16(af[mi], bfr[ni], acc[mi][ni]);
  }

#pragma unroll
  for (int mi = 0; mi < 4; ++mi) {
#pragma unroll
    for (int ni = 0; ni < 4; ++ni) {
      int col = n0 + wn + ni * 16 + r16;
      float bv = bias[col];
#pragma unroll
      for (int r = 0; r < 4; ++r) {
        int row = m0 + wm + mi * 16 + quad * 4 + r;
        y[(size_t)row * 512 + coff + col] = f2bf(acc[mi][ni][r] + bv);
      }
    }
  }
}

// ---------------------------------------------------------------------------
// Flash attention v11: R5 structure + T5 s_setprio around the MFMA clusters.
// Regime (rule 23): 2 independent blocks/CU, barrier-synced only internally
// -> cross-block phase diversity; setprio(1) during a block's QK/PV MFMA
// chains preempts the other block's staging/exp VALU (m191 attn precedent
// +4-7%; m190's GEMM-null was a single-block lockstep config). Revert if
// null. All else identical to R5 (measured 46.8 mha / ~31 lofi, R11: 45.4).
// ---------------------------------------------------------------------------
template<int QG>
__global__ __launch_bounds__(256, 2)
void flash_attn9(const ushort_t* __restrict__ Q, int qs, int q_ch,
                 const ushort_t* __restrict__ Kg, int ks, int k_ch,
                 const ushort_t* __restrict__ vT,
                 ushort_t* __restrict__ O, int os, int o_ch,
                 int N)
{
  // [buf][64 rows][64 bf16] ; K rows = keys (cols d), V rows = d (cols keys)
  __shared__ __align__(16) ushort_t Ks[2][64 * 64];
  __shared__ __align__(16) ushort_t Vs[2][64 * 64];

  const int H = gridDim.y;
  const int tid = threadIdx.x, wave = tid >> 6, lane = tid & 63;
  const int c = lane & 31, hh = lane >> 5;

  // T1: chunked XCD remap (bijective; nwg % 8 == 0).
  const int nwg = gridDim.x * H * gridDim.z;
  const int lin = blockIdx.x + gridDim.x * (blockIdx.y + H * blockIdx.z);
  const int logical = (lin & 7) * (nwg >> 3) + (lin >> 3);
  const int QBS = 8 / QG;                  // q-blocks per (b,h)
  const int qb = logical & (QBS - 1);
  const int t8 = logical / QBS;
  const int b = (H == 8) ? (t8 >> 3) : (t8 >> 2);
  const int h = t8 - b * H;
  const int q0 = qb * (128 * QG) + wave * (32 * QG);

  // Q fragments: B-operand layout B[k=d][n=query]: lane (hh,c) holds
  // query q0+qg*32+c, d = s*16 + hh*8 + j -> qf[qg][s] at byte-col s*16+hh*8.
  bf16x8 qf[QG][4];
#pragma unroll
  for (int qg = 0; qg < QG; ++qg) {
    const ushort_t* qp =
        Q + ((size_t)b * N + q0 + qg * 32 + c) * qs + q_ch + h * 64 + hh * 8;
#pragma unroll
    for (int s = 0; s < 4; ++s) qf[qg][s] = *(const bf16x8*)&qp[s * 16];
  }
  const ushort_t* kbase = Kg + ((size_t)b * N) * ks + k_ch + h * 64;
  const ushort_t* vbase = vT + ((size_t)(b * H + h) * 64) * N;

  f32x16 oacc[QG][2];
#pragma unroll
  for (int qg = 0; qg < QG; ++qg)
#pragma unroll
    for (int i = 0; i < 16; ++i) { oacc[qg][0][i] = 0.f; oacc[qg][1][i] = 0.f; }
  float l_acc[QG];
#pragma unroll
  for (int qg = 0; qg < QG; ++qg) l_acc[qg] = 0.f;

  auto stage = [&](int s0, int buf) {
#pragma unroll
    for (int p = 0; p < 4; ++p) {
      int wp = p * 4 + wave;                 // 0..15: 0..7 -> K, 8..15 -> V
      int lc = ((wp & 7) << 6) + lane;       // chunk 0..511 within tile
      int row = lc >> 3, cc = lc & 7;
      int e8 = ((cc ^ (row & 7)) * 8);       // inverse-swizzled SOURCE chunk
      if (wp < 8) gl_lds16(kbase + (size_t)(s0 + row) * ks + e8, &Ks[buf][lc * 8]);
      else        gl_lds16(vbase + (size_t)row * N + s0 + e8,    &Vs[buf][lc * 8]);
    }
  };

  stage(0, 0);
  const int NT = N >> 6;
  for (int it = 0; it < NT; ++it) {
    const int cur = it & 1;
    __syncthreads();                     // vmcnt(0) drain: tile `it` staged;
                                         // also fences prev-iter LDS readers
    if (it + 1 < NT) stage((it + 1) << 6, cur ^ 1);

    bf16x8 Bf[QG][4];                    // PV B-operand, k-steps of 16 keys
#pragma unroll
    for (int kb = 0; kb < 2; ++kb) {
      // K fragments shared across the QG query groups.
      const int krow = kb * 32 + c;
      const ushort_t* kr = &Ks[cur][krow * 64];
      bf16x8 kf[4];
#pragma unroll
      for (int s = 0; s < 4; ++s)
        kf[s] = *(const bf16x8*)&kr[(((s << 1) + hh) ^ (krow & 7)) * 8];

#pragma unroll
      for (int qg = 0; qg < QG; ++qg) {
        // S^T block: A = K rows (m = key kb*32 + (lane&31)), B = Q[qg].
        f32x16 z;
#pragma unroll
        for (int i = 0; i < 16; ++i) z[i] = 0.f;
        __builtin_amdgcn_s_setprio(1);
#pragma unroll
        for (int s = 0; s < 4; ++s) z = mfma32(kf[s], qf[qg][s], z);
        __builtin_amdgcn_s_setprio(0);
        // exp + pack: reg r <-> key kb*32 + (r&3) + 8*(r>>2) + 4*hh
        float ts = 0.f;
        unsigned W[8];
#pragma unroll
        for (int t = 0; t < 8; ++t) {
          float p0 = __builtin_amdgcn_exp2f(z[2 * t]);
          float p1 = __builtin_amdgcn_exp2f(z[2 * t + 1]);
          ts += p0 + p1;
          W[t] = cvtpk_bf16(p0, p1);
        }
        l_acc[qg] += ts;
        // B[k=hh*8+j][n=c] per k-step, element i = keys {s*16+hh*8+2i, +1}:
        //  u0=[W0_lo|W2_lo] u1=[W1_lo|W3_lo] u2=[W0_hi|W2_hi] u3=[W1_hi|W3_hi]
        // swap(a,b): a=[a_lo|b_lo], b=[a_hi|b_hi] -> swap(W0,W2)=(u0,u2),
        // swap(W1,W3)=(u1,u3); W4..W7 for the second k-step.  [verified R4]
        union U8 { bf16x8 f; unsigned u[4]; } f0, f1;
        unsigned a0 = W[0], b0 = W[2]; pl32swap(a0, b0);
        unsigned a1 = W[1], b1 = W[3]; pl32swap(a1, b1);
        f0.u[0] = a0; f0.u[1] = a1; f0.u[2] = b0; f0.u[3] = b1;
        unsigned a2 = W[4], b2 = W[6]; pl32swap(a2, b2);
        unsigned a3 = W[5], b3 = W[7]; pl32swap(a3, b3);
        f1.u[0] = a2; f1.u[1] = a3; f1.u[2] = b2; f1.u[3] = b3;
        Bf[qg][kb * 2]     = f0.f;
        Bf[qg][kb * 2 + 1] = f1.f;
      }
    }

    // PV: O^T = mfma32(A = V^T (m = d), B = P), k-steps of 16 keys; V
    // fragments shared across query groups.
#pragma unroll
    for (int db = 0; db < 2; ++db) {
      const int vrow = db * 32 + c;
      const ushort_t* vr = &Vs[cur][vrow * 64];
      bf16x8 vf[4];
#pragma unroll
      for (int s = 0; s < 4; ++s)
        vf[s] = *(const bf16x8*)&vr[(((s << 1) + hh) ^ (vrow & 7)) * 8];
      __builtin_amdgcn_s_setprio(1);
#pragma unroll
      for (int qg = 0; qg < QG; ++qg)
#pragma unroll
        for (int s = 0; s < 4; ++s)
          oacc[qg][db] = mfma32(vf[s], Bf[qg][s], oacc[qg][db]);
      __builtin_amdgcn_s_setprio(0);
    }
  }

  // epilogue: l(query c) = l_acc(h0) + l_acc(h1); O^T reg r of dblk db is
  // d = db*32 + (r&3) + 8*(r>>2) + 4*hh, query = c.
#pragma unroll
  for (int qg = 0; qg < QG; ++qg) {
    float l = l_acc[qg] + __shfl_xor(l_acc[qg], 32);
    float inv = 1.f / l;
    ushort_t* op = O + ((size_t)b * N + q0 + qg * 32 + c) * os + o_ch + h * 64;
#pragma unroll
    for (int db = 0; db < 2; ++db) {
#pragma unroll
      for (int g = 0; g < 4; ++g) {
        uint2 pkv;
        pkv.x = cvtpk_bf16(oacc[qg][db][4 * g + 0] * inv, oacc[qg][db][4 * g + 1] * inv);
        pkv.y = cvtpk_bf16(oacc[qg][db][4 * g + 2] * inv, oacc[qg][db][4 * g + 3] * inv);
        *(uint2*)&op[db * 32 + g * 8 + hh * 4] = pkv;
      }
    }
  }
}

// ---------------------------------------------------------------------------
// V transpose: in [B*N][ld] bf16 (channel ch, head h) -> out [B*H][64][N]
// ---------------------------------------------------------------------------
__global__ __launch_bounds__(256)
void transpose_v(const ushort_t* __restrict__ in, int ld, int ch,
                 ushort_t* __restrict__ out, int N, int H)
{
  __shared__ __align__(16) ushort_t T[64][72];
  const int s0 = blockIdx.x * 64, h = blockIdx.y, b = blockIdx.z;
  const int tid = threadIdx.x;
#pragma unroll
  for (int p = 0; p < 2; ++p) {
    int c = p * 256 + tid;
    int sr = c >> 3, d0 = (c & 7) * 8;
    *(uint4*)&T[sr][d0] =
        *(const uint4*)&in[((size_t)b * N + s0 + sr) * ld + ch + h * 64 + d0];
  }
  __syncthreads();
  const int d = tid >> 2, sp = (tid & 3) * 16;
  union { uint4 v; ushort_t u[8]; } A, B;
#pragma unroll
  for (int j = 0; j < 8; ++j) { A.u[j] = T[sp + j][d]; B.u[j] = T[sp + 8 + j][d]; }
  ushort_t* op = out + ((size_t)(b * H + h) * 64 + d) * N + s0 + sp;
  *(uint4*)&op[0] = A.v;
  *(uint4*)&op[8] = B.v;
}

// ---------------------------------------------------------------------------
// hifi window attention (2x2 windows, 4 heads). qkv rows stride ld; per-token
// layout [3][4 heads][64]. Output stride 512, cols 0..255.
// (q here is NOT pre-scaled by the GEMM; keeps its own 0.125 + __expf.)
// ---------------------------------------------------------------------------
__global__ __launch_bounds__(256)
void hifi_win(const ushort_t* __restrict__ qkv, int ld, ushort_t* __restrict__ out)
{
  const int bg = blockIdx.x;
  const int b = bg >> 8, g = bg & 255;
  const int head = threadIdx.x >> 6, lane = threadIdx.x & 63;
  const int gh = g >> 4, gw = g & 15;

  int n[4];
  float q[4], k[4], v[4];
#pragma unroll
  for (int t = 0; t < 4; ++t) {
    n[t] = (gh * 2 + (t >> 1)) * 32 + gw * 2 + (t & 1);
    size_t base = ((size_t)b * 1024 + n[t]) * ld + head * 64 + lane;
    q[t] = bf2f(qkv[base]);
    k[t] = bf2f(qkv[base + 256]);
    v[t] = bf2f(qkv[base + 512]);
  }
  float sc[4][4];
#pragma unroll
  for (int t = 0; t < 4; ++t)
#pragma unroll
    for (int s = 0; s < 4; ++s) {
      float p = q[t] * k[s];
#pragma unroll
      for (int off = 32; off >= 1; off >>= 1) p += __shfl_xor(p, off);
      sc[t][s] = p * 0.125f;
    }
#pragma unroll
  for (int t = 0; t < 4; ++t) {
    float m = fmaxf(fmaxf(sc[t][0], sc[t][1]), fmaxf(sc[t][2], sc[t][3]));
    float p0 = __expf(sc[t][0] - m), p1 = __expf(sc[t][1] - m);
    float p2 = __expf(sc[t][2] - m), p3 = __expf(sc[t][3] - m);
    float sum = p0 + p1 + p2 + p3;
    float o = (p0 * v[0] + p1 * v[1] + p2 * v[2] + p3 * v[3]) / sum;
    out[((size_t)b * 1024 + n[t]) * 512 + head * 64 + lane] = f2bf(o);
  }
}

// ---------------------------------------------------------------------------
// Merged weight prep: 7 transposes W[K][N] fp32 -> WT[N][K] bf16 in one launch.
// ---------------------------------------------------------------------------
struct WEnt { const float* W; ushort_t* WT; int K; int N; };
struct WArgs { WEnt e[7]; };

__global__ __launch_bounds__(256)
void w_prep(WArgs a)
{
  WEnt w = a.e[blockIdx.z];
  if ((int)blockIdx.x >= (w.K >> 6) || (int)blockIdx.y >= (w.N >> 6)) return;
  __shared__ float T[64][65];
  const int k0 = blockIdx.x * 64, n0 = blockIdx.y * 64;
  const int tid = threadIdx.x;
#pragma unroll
  for (int p = 0; p < 4; ++p) {
    int c = p * 256 + tid;
    int kr = c >> 4, f4 = (c & 15) * 4;
    float4 v = *(const float4*)&w.W[(size_t)(k0 + kr) * w.N + n0 + f4];
    T[f4 + 0][kr] = v.x; T[f4 + 1][kr] = v.y;
    T[f4 + 2][kr] = v.z; T[f4 + 3][kr] = v.w;
  }
  __syncthreads();
  const int nl = tid >> 2, kp = (tid & 3) * 16;
  union { uint4 v; ushort_t u[8]; } A, B;
#pragma unroll
  for (int j = 0; j < 8; ++j) {
    A.u[j] = f2bf(T[nl][kp + j]);
    B.u[j] = f2bf(T[nl][kp + 8 + j]);
  }
  ushort_t* op = w.WT + (size_t)(n0 + nl) * w.K + k0 + kp;
  *(uint4*)&op[0] = A.v;
  *(uint4*)&op[8] = B.v;
}

// xpe = bf16(x + pos_emb), vectorized x4
__global__ void add_pos(const float* __restrict__ x, const float* __restrict__ pos,
                        ushort_t* __restrict__ xpe)
{
  int idx = blockIdx.x * 256 + threadIdx.x;
  int e = idx * 4;
  float4 xv = *(const float4*)&x[e];
  float4 pv = *(const float4*)&pos[e & (512 * 1024 - 1)];
  uint2 pk;
  pk.x = pk_bf16(xv.x + pv.x, xv.y + pv.y);
  pk.y = pk_bf16(xv.z + pv.z, xv.w + pv.w);
  *(uint2*)&xpe[e] = pk;
}

extern "C" void kernel_launch(void* const* d_in, const int* in_sizes, int n_in,
                              void* d_out, int out_size, void* d_ws, size_t ws_size,
                              hipStream_t stream)
{
  const float* x         = (const float*)d_in[0];
  const float* pos       = (const float*)d_in[1];
  const float* l_q_w     = (const float*)d_in[2];
  const float* l_kv_w    = (const float*)d_in[3];
  const float* l_proj_w  = (const float*)d_in[4];
  const float* l_proj_b  = (const float*)d_in[5];
  const float* h_qkv_w   = (const float*)d_in[6];
  const float* h_proj_w  = (const float*)d_in[7];
  const float* h_proj_b  = (const float*)d_in[8];
  const float* in_proj_w = (const float*)d_in[9];
  const float* in_proj_b = (const float*)d_in[10];
  const float* out_proj_w= (const float*)d_in[11];
  const float* out_proj_b= (const float*)d_in[12];
  float* out = (float*)d_out;

  // 0.125 * log2(e): flash_attn uses exp2 directly.
  const float QSCALE = 0.125f * 1.44269504f;

  char* ws = (char*)d_ws;
  ushort_t* xpe = (ushort_t*)(ws);                       // 16 MB @ 0
  ushort_t* y   = (ushort_t*)(ws + (size_t)16777216);    // 16 MB @ 16M
  ushort_t* F   = (ushort_t*)(ws + (size_t)33554432);    // 48 MB @ 32M (fused acts)
  ushort_t* rB  = (ushort_t*)(ws + (size_t)83886080);    // 16 MB @ 80M
  ushort_t* wb  = (ushort_t*)(ws + (size_t)100663296);   // ~4 MB @ 96M (weights)

  // fused BT for the xpe GEMM: rows [0,768)=h_qkv, [768,1024)=l_q, [1024,1536)=l_kv
  ushort_t* F_T      = wb;                        // 1536 x 512
  ushort_t* h_projT  = wb + 786432;               // 256 x 256
  ushort_t* l_projT  = wb + 851968;               // 256 x 256
  ushort_t* in_projT = wb + 917504;               // 1536 x 512
  ushort_t* out_projT= wb + 1703936;              // 512 x 512

  const int M = 16384;
  ushort_t* vT_lo = xpe;   // 8 MB; xpe dead after fused GEMM
  ushort_t* vT_m  = rB;    // 16 MB; rB dead after lproj

  WArgs wa;
  wa.e[0] = {h_qkv_w,   F_T,                 512, 768};
  wa.e[1] = {l_q_w,     F_T + 768 * 512,     512, 256};
  wa.e[2] = {l_kv_w,    F_T + 1024 * 512,    512, 512};
  wa.e[3] = {h_proj_w,  h_projT,             256, 256};
  wa.e[4] = {l_proj_w,  l_projT,             256, 256};
  wa.e[5] = {in_proj_w, in_projT,            512, 1536};
  wa.e[6] = {out_proj_w,out_projT,           512, 512};
  w_prep<<<dim3(8, 24, 7), dim3(256), 0, stream>>>(wa);

  add_pos<<<dim3(8192), dim3(256), 0, stream>>>(x, pos, xpe);

  // 1. fused qkv GEMM: [M,512] x [512,1536] -> F (lofi q cols pre-scaled)
  gemm_bt<<<dim3(M / 128, 12), dim3(256), 0, stream>>>(
      xpe, 512, F_T, nullptr, F, nullptr, 1536, 0, 512, QSCALE, 768, 1024);
  // 2. hifi window attention -> rB cols [0,256)
  hifi_win<<<dim3(4096), dim3(256), 0, stream>>>(F, 1536, rB);
  // 3. transpose lofi V (F cols 1280..1535) -> vT_lo (xpe region, now dead)
  transpose_v<<<dim3(16, 4, 16), dim3(256), 0, stream>>>(
      F, 1536, 1280, vT_lo, 1024, 4);
  // 4. lofi attention (4 heads) -> rB cols [256,512)   (QG=1: 512 blocks)
  flash_attn9<1><<<dim3(8, 4, 16), dim3(256), 0, stream>>>(
      F, 1536, 768, F, 1536, 1024, vT_lo, rB, 512, 256, 1024);
  // 5+6. hifi & lofi proj merged -> y  (512 blocks = 2/CU)
  gemm_proj<<<dim3(128, 4), dim3(256), 0, stream>>>(
      rB, h_projT, l_projT, h_proj_b, l_proj_b, y);
  // 7. mha qkv: [M,512] x [512,1536] -> F (q cols pre-scaled)
  gemm_bt<<<dim3(M / 128, 12), dim3(256), 0, stream>>>(
      y, 512, in_projT, in_proj_b, F, nullptr, 1536, 0, 512, QSCALE, 0, 512);
  // 8. transpose mha V (F cols 1024..1535) -> vT_m (rB dead now)
  transpose_v<<<dim3(16, 8, 16), dim3(256), 0, stream>>>(
      F, 1536, 1024, vT_m, 1024, 8);
  // 9. mha attention (8 heads) -> xpe region [M,512]  (QG=2: 64 q/wave,
  //    512 blocks = 2/CU; two independent chains per wave)
  flash_attn9<2><<<dim3(4, 8, 16), dim3(256), 0, stream>>>(
      F, 1536, 0, F, 1536, 512, vT_m, xpe, 512, 0, 1024);
  // 10. out proj -> d_out fp32
  gemm_bt<<<dim3(M / 128, 4), dim3(256), 0, stream>>>(
      xpe, 512, out_projT, out_proj_b, nullptr, out, 512, 0, 512, 1.0f, 0, 0);
}